// Round 12
// baseline (225.002 us; speedup 1.0000x reference)
//
#include <hip/hip_runtime.h>
#include <hip/hip_bf16.h>
#include <math.h>

#define NB 4
#define NN 32768
#define MM 32768
#define KK 16
#define HID 64
#define DIM 32
#define ENK (NN*KK)              // 524288 elements per batch (2^19)
#define EF  524288.0f
#define CNTG (16.0f*EF)
#define MASK_NEG (-60.0f)        // finite mask: exp(-60)=8.8e-27; all-masked row -> exact uniform

// ---- workspace u32/float offsets (small region) ----
#define WS_STATS1 0        // [4][16]  : slp[4], M10[10], pad
#define WS_STATS2 64       // [4][1056]: spe[32], Mpe[32*32]  (logical channel space)
#define WS_B1F    5312     // [4][64] f32
#define WS_WA1H   5568     // [4][64][16] u32 (half2 folded attn_w1, columns gamma-permuted)
#define WS_BA1F   9664     // [4][64] f32
#define WS_W2H    9920     // [32][32] u32 (half2 pre_w2, natural slot order)
#define WS_WA2H   10944    // [32][2][16] u32 (half2 attn_w2, delta-permuted per (j,h))
#define WS_W1H    11968    // [4][64][2] u32 (half2 folded pre_w1)
#define PE_BYTE_OFF 65536ull

// pe storage (frag order): tile of 32 elems = 1024 u16 at e0*32.
// lane (c,h) owns element e0+c, channels gamma(h,p,lsb)=16(p>>2)+8((p>>1)&1)+4h+2(p&1)+lsb,
// stored as 16 u16 at (h*32+c)*16.  Inverse: for channel k:
//   h=(k>>2)&1, p=4*(k>>4)+2*((k>>3)&1)+((k>>1)&1), lsb=k&1
//   u16 off within tile = h*512 + (elem&31)*16 + p*2 + lsb

typedef _Float16 h2v __attribute__((ext_vector_type(2)));
typedef _Float16 h8v __attribute__((ext_vector_type(8)));
typedef float f16v __attribute__((ext_vector_type(16)));

#if defined(__has_builtin)
#if __has_builtin(__builtin_amdgcn_fdot2)
#define USE_FDOT2 1
#endif
#endif
#ifndef USE_FDOT2
#define USE_FDOT2 0
#endif

__device__ __forceinline__ float dot2f(unsigned w, unsigned x, float acc) {
#if USE_FDOT2
  return __builtin_amdgcn_fdot2(__builtin_bit_cast(h2v, w),
                                __builtin_bit_cast(h2v, x), acc, false);
#else
  h2v a = __builtin_bit_cast(h2v, w);
  h2v b = __builtin_bit_cast(h2v, x);
  acc = fmaf((float)a[0], (float)b[0], acc);
  return fmaf((float)a[1], (float)b[1], acc);
#endif
}

__device__ __forceinline__ unsigned pkh(float a, float b) {
  return __builtin_bit_cast(unsigned, __builtin_amdgcn_cvt_pkrtz(a, b));
}

__device__ __forceinline__ f16v mfma16(uint4 a, uint4 b, f16v c) {
  return __builtin_amdgcn_mfma_f32_32x32x16_f16(
      __builtin_bit_cast(h8v, a), __builtin_bit_cast(h8v, b), c, 0, 0, 0);
}

template<int NV>
__device__ __forceinline__ void block_reduce_atomic(float* v, float* dst) {
  #pragma unroll
  for (int i = 0; i < NV; ++i) {
    float x = v[i];
    x += __shfl_down(x, 32);
    x += __shfl_down(x, 16);
    x += __shfl_down(x, 8);
    x += __shfl_down(x, 4);
    x += __shfl_down(x, 2);
    x += __shfl_down(x, 1);
    v[i] = x;
  }
  __shared__ float red[4][NV];
  const int lane = threadIdx.x & 63;
  const int wv = threadIdx.x >> 6;
  if (lane == 0) {
    #pragma unroll
    for (int i = 0; i < NV; ++i) red[wv][i] = v[i];
  }
  __syncthreads();
  if (threadIdx.x < NV) {
    float t = red[0][threadIdx.x] + red[1][threadIdx.x] +
              red[2][threadIdx.x] + red[3][threadIdx.x];
    atomicAdd(dst + threadIdx.x, t);
  }
}

__device__ __forceinline__ void compute_lp(const float* __restrict__ qb,
                                           const float* __restrict__ kb,
                                           int n, int idx,
                                           float& lp0, float& lp1, float& lp2, float& lp3) {
  float dx = kb[idx]        - qb[n];
  float dy = kb[MM + idx]   - qb[NN + n];
  float dz = kb[2*MM + idx] - qb[2*NN + n];
  float dist = sqrtf(fmaf(dx, dx, fmaf(dy, dy, dz*dz)));
  float inv = 1.0f / fmaxf(dist, 1e-12f);
  lp0 = dx * inv; lp1 = dy * inv; lp2 = dz * inv; lp3 = dist;
}

// ---------------- Pass A: lp moments (grid NB*256 + 1; last block packs weights) ----------------
__global__ __launch_bounds__(256) void k_lpmom(
    const float* __restrict__ q_xyzs, const float* __restrict__ k_xyzs,
    const int* __restrict__ knn_idx,
    const float* __restrict__ w2, const float* __restrict__ wa2,
    float* __restrict__ ws)
{
  if (blockIdx.x == NB*256) {                 // weight-pack block
    int t = threadIdx.x;
    unsigned* wsu = (unsigned*)ws;
    if (t < 32) {
      const float* src = w2 + t*64;
      unsigned* dst = wsu + WS_W2H + t*32;
      #pragma unroll
      for (int i = 0; i < 32; ++i) dst[i] = pkh(src[2*i], src[2*i+1]);
    } else if (t >= 64 && t < 128) {
      // attn_w2 delta-permuted pack: slot (j, h, kc2, jj) = Wa2[j][delta(kc2,h,jj)]
      int j  = (t - 64) & 31;
      int hh = (t - 64) >> 5;
      const float* src = wa2 + j*64;
      unsigned* dst = wsu + WS_WA2H + (j*2 + hh)*16;
      #pragma unroll
      for (int kc2 = 0; kc2 < 4; ++kc2)
        #pragma unroll
        for (int pb = 0; pb < 4; ++pb) {
          int base = 32*(kc2>>1) + 16*(kc2&1) + 8*(pb>>1) + 4*hh + 2*(pb&1);
          dst[kc2*4 + pb] = pkh(src[base], src[base+1]);
        }
    }
    return;
  }
  const int b   = blockIdx.x >> 8;
  const int blk = blockIdx.x & 255;
  const float* qb = q_xyzs + b*3*NN;
  const float* kb = k_xyzs + b*3*MM;
  const int* idxb = knn_idx + b*ENK;

  float a[14];
  #pragma unroll
  for (int i = 0; i < 14; ++i) a[i] = 0.f;

  for (int it = 0; it < 8; ++it) {
    int el = (blk*8 + it)*256 + threadIdx.x;
    int n = el >> 4;
    int idx = idxb[el];
    float lp0, lp1, lp2, lp3;
    compute_lp(qb, kb, n, idx, lp0, lp1, lp2, lp3);
    a[0] += lp0; a[1] += lp1; a[2] += lp2; a[3] += lp3;
    a[4] = fmaf(lp0, lp0, a[4]);  a[5] = fmaf(lp0, lp1, a[5]);
    a[6] = fmaf(lp0, lp2, a[6]);  a[7] = fmaf(lp0, lp3, a[7]);
    a[8] = fmaf(lp1, lp1, a[8]);  a[9] = fmaf(lp1, lp2, a[9]);
    a[10] = fmaf(lp1, lp3, a[10]); a[11] = fmaf(lp2, lp2, a[11]);
    a[12] = fmaf(lp2, lp3, a[12]); a[13] = fmaf(lp3, lp3, a[13]);
  }
  block_reduce_atomic<14>(a, ws + WS_STATS1 + b*16);
}

// ---------------- Fold GN1 into W1 (writes half2-packed + f32 bias) ----------------
__global__ __launch_bounds__(64) void k_fold1(
    const float* __restrict__ w1, const float* __restrict__ b1,
    const float* __restrict__ gw, const float* __restrict__ gb,
    float* __restrict__ ws)
{
  int b = blockIdx.x, o = threadIdx.x;
  const float* st = ws + WS_STATS1 + b*16;
  float4 w = ((const float4*)w1)[o];
  float bb = b1[o];
  float dot = w.x*st[0] + w.y*st[1] + w.z*st[2] + w.w*st[3];
  float quad = w.x*w.x*st[4] + w.y*w.y*st[8] + w.z*w.z*st[11] + w.w*w.w*st[13]
    + 2.f*(w.x*w.y*st[5] + w.x*w.z*st[6] + w.x*w.w*st[7]
         + w.y*w.z*st[9] + w.y*w.w*st[10] + w.z*w.w*st[12]);
  float sum = dot + EF*bb;
  float ssq = quad + 2.f*bb*dot + EF*bb*bb;
  #pragma unroll
  for (int m = 1; m < 16; m <<= 1) {
    sum += __shfl_xor(sum, m);
    ssq += __shfl_xor(ssq, m);
  }
  float mu  = sum / CNTG;
  float var = ssq / CNTG - mu*mu;
  float sc  = rsqrtf(var + 1e-5f) * gw[o];
  unsigned* w1hd = (unsigned*)ws + WS_W1H + b*128;
  w1hd[o*2]   = pkh(w.x*sc, w.y*sc);
  w1hd[o*2+1] = pkh(w.z*sc, w.w*sc);
  (ws + WS_B1F)[b*64 + o] = (bb - mu)*sc + gb[o];
}

// ---------------- Pass B (MFMA): gather -> h1 -> pe = W2 h1 + b2, store frag-order ----------------
__global__ __launch_bounds__(256) void k_pe(
    const float* __restrict__ q_xyzs, const float* __restrict__ k_xyzs,
    const int* __restrict__ knn_idx, const float* __restrict__ b2,
    const float* __restrict__ ws, unsigned short* __restrict__ peh_ws)
{
  const int b  = blockIdx.x >> 8;           // 256 blocks per batch (uniform)
  const int l  = threadIdx.x & 63;
  const int wv = threadIdx.x >> 6;
  const int c  = l & 31;
  const int h  = l >> 5;
  const float* qb = q_xyzs + b*3*NN;
  const float* kb = k_xyzs + b*3*MM;

  const unsigned* w1h = (const unsigned*)ws + WS_W1H + b*128;
  const float* b1f = ws + WS_B1F + b*64;
  unsigned w01[32], w23[32];
  float bch[32];
  #pragma unroll
  for (int kc = 0; kc < 4; ++kc)
    #pragma unroll
    for (int jj = 0; jj < 8; ++jj) {
      int ch = kc*16 + h*8 + jj;
      w01[kc*8+jj] = w1h[ch*2];
      w23[kc*8+jj] = w1h[ch*2+1];
      bch[kc*8+jj] = b1f[ch];
    }
  const unsigned* w2h = (const unsigned*)ws + WS_W2H;
  uint4 A2[4];
  #pragma unroll
  for (int kc = 0; kc < 4; ++kc)
    A2[kc] = *(const uint4*)(w2h + c*32 + kc*8 + h*4);
  float bias2[16];
  #pragma unroll
  for (int r = 0; r < 16; ++r) bias2[r] = b2[(r&3) + 8*(r>>2) + 4*h];

  const int e0w = blockIdx.x*2048 + wv*512;

  // prefetch tile 0's gather
  int idx0 = knn_idx[e0w + c];
  float gxn = kb[idx0], gyn = kb[MM + idx0], gzn = kb[2*MM + idx0];

  #pragma unroll 1
  for (int tt = 0; tt < 16; ++tt) {
    const int et = e0w + tt*32;
    const int e = et + c;
    int n = (e & (ENK-1)) >> 4;
    float gx = gxn, gy = gyn, gz = gzn;
    if (tt < 15) {
      int idn = knn_idx[e + 32];
      gxn = kb[idn]; gyn = kb[MM + idn]; gzn = kb[2*MM + idn];
    }
    float dx = gx - qb[n];
    float dy = gy - qb[NN + n];
    float dz = gz - qb[2*NN + n];
    float dist = sqrtf(fmaf(dx, dx, fmaf(dy, dy, dz*dz)));
    float inv = 1.0f / fmaxf(dist, 1e-12f);
    unsigned lp01 = pkh(dx*inv, dy*inv), lp23 = pkh(dz*inv, dist);

    uint4 Bf[4];
    #pragma unroll
    for (int kc = 0; kc < 4; ++kc) {
      unsigned bb[4];
      #pragma unroll
      for (int q = 0; q < 4; ++q) {
        int i0 = kc*8 + 2*q, i1 = i0 + 1;
        float xa = fmaxf(dot2f(w01[i0], lp01, dot2f(w23[i0], lp23, bch[i0])), 0.f);
        float xb = fmaxf(dot2f(w01[i1], lp01, dot2f(w23[i1], lp23, bch[i1])), 0.f);
        bb[q] = pkh(xa, xb);
      }
      Bf[kc] = make_uint4(bb[0], bb[1], bb[2], bb[3]);
    }

    f16v acc;
    #pragma unroll
    for (int r = 0; r < 16; ++r) acc[r] = bias2[r];
    #pragma unroll
    for (int kc = 0; kc < 4; ++kc) acc = mfma16(A2[kc], Bf[kc], acc);

    // store C-layout packs directly (frag order) -- no exchange
    unsigned u[8];
    #pragma unroll
    for (int p = 0; p < 8; ++p) u[p] = pkh(acc[2*p], acc[2*p+1]);
    uint4* d = (uint4*)(peh_ws + (size_t)et*32 + (size_t)(h*32 + c)*16);
    d[0] = make_uint4(u[0], u[1], u[2], u[3]);
    d[1] = make_uint4(u[4], u[5], u[6], u[7]);
  }
}

// ---------------- Pass B2: pe moments via MFMA (M = pe^T pe, spe = sum pe) ----------------
__global__ __launch_bounds__(256) void k_pemom(
    const unsigned short* __restrict__ peh_ws, float* __restrict__ ws)
{
  const int b   = blockIdx.x >> 7;          // 128 blocks per batch
  const int blk = blockIdx.x & 127;
  const int wv  = threadIdx.x >> 6;
  const int l   = threadIdx.x & 63;
  const int c   = l & 31;                   // logical channel
  const int h   = l >> 5;

  // gamma-inverse addressing for channel c
  const int hc  = (c >> 2) & 1;
  const int pc  = ((c >> 4) << 2) + (((c >> 3) & 1) << 1) + ((c >> 1) & 1);
  const int offc = hc*512 + pc*2 + (c & 1);     // u16 units within tile

  const size_t ebase = (size_t)b*ENK + ((size_t)(blk*4 + wv))*1024;

  f16v acc;
  #pragma unroll
  for (int i = 0; i < 16; ++i) acc[i] = 0.f;
  float spe = 0.f;
  const unsigned ONE = pkh(1.f, 1.f);

  for (int t = 0; t < 64; ++t) {
    const unsigned short* p = peh_ws + ebase*32 + (size_t)(t>>1)*1024
                              + (t&1)*256 + h*128 + offc;
    unsigned u0 = (unsigned)p[0]  | ((unsigned)p[16] << 16);
    unsigned u1 = (unsigned)p[32] | ((unsigned)p[48] << 16);
    unsigned u2 = (unsigned)p[64] | ((unsigned)p[80] << 16);
    unsigned u3 = (unsigned)p[96] | ((unsigned)p[112] << 16);
    uint4 uu = make_uint4(u0, u1, u2, u3);
    h8v frag = __builtin_bit_cast(h8v, uu);
    acc = __builtin_amdgcn_mfma_f32_32x32x16_f16(frag, frag, acc, 0, 0, 0);
    spe = dot2f(u0, ONE, spe);
    spe = dot2f(u1, ONE, spe);
    spe = dot2f(u2, ONE, spe);
    spe = dot2f(u3, ONE, spe);
  }

  float* st2 = ws + WS_STATS2 + b*1056;
  spe += __shfl_down(spe, 32);
  if (l < 32) atomicAdd(st2 + c, spe);
  #pragma unroll
  for (int r = 0; r < 16; ++r) {
    int row = (r & 3) + 8*(r >> 2) + 4*h;
    atomicAdd(st2 + 32 + row*32 + c, acc[r]);
  }
}

// ---------------- Fold GN2 into Wa1, write half2-packed, columns gamma-permuted ----------------
__global__ __launch_bounds__(64) void k_fold2m(
    const float* __restrict__ wa1, const float* __restrict__ ba1,
    const float* __restrict__ gw2, const float* __restrict__ gb2,
    float* __restrict__ ws)
{
  int b = blockIdx.x, o = threadIdx.x;
  const float* st = ws + WS_STATS2 + b*1056;
  float w[32];
  const float4* wrow = (const float4*)wa1 + o*8;
  #pragma unroll
  for (int i = 0; i < 8; ++i) {
    float4 t = wrow[i];
    w[4*i] = t.x; w[4*i+1] = t.y; w[4*i+2] = t.z; w[4*i+3] = t.w;
  }
  float dot = 0.f;
  #pragma unroll
  for (int cc = 0; cc < 32; ++cc) dot = fmaf(w[cc], st[cc], dot);
  float quad = 0.f;
  #pragma unroll
  for (int rr = 0; rr < 32; ++rr) {
    const float* Mr = st + 32 + rr*32;
    float mr = 0.f;
    #pragma unroll
    for (int cc = 0; cc < 32; ++cc) mr = fmaf(Mr[cc], w[cc], mr);
    quad = fmaf(w[rr], mr, quad);
  }
  float bb = ba1[o];
  float sum = dot + EF*bb;
  float ssq = quad + 2.f*bb*dot + EF*bb*bb;
  #pragma unroll
  for (int m = 1; m < 16; m <<= 1) {
    sum += __shfl_xor(sum, m);
    ssq += __shfl_xor(ssq, m);
  }
  float mu  = sum / CNTG;
  float var = ssq / CNTG - mu*mu;
  float sc  = rsqrtf(var + 1e-5f) * gw2[o];
  unsigned* dst = (unsigned*)ws + WS_WA1H + (b*64 + o)*16;
  #pragma unroll
  for (int kc = 0; kc < 2; ++kc)
    #pragma unroll
    for (int hh = 0; hh < 2; ++hh)
      #pragma unroll
      for (int p = 0; p < 4; ++p) {
        int base = 16*kc + 8*(p>>1) + 4*hh + 2*(p&1);
        dst[kc*8 + hh*4 + p] = pkh(w[base]*sc, w[base+1]*sc);
      }
  (ws + WS_BA1F)[b*64 + o] = (bb - mu)*sc + gb2[o];
}

// ---------------- Pass C (MFMA): h2, logits, masked softmax, output -- exchange-free ----------------
__global__ __launch_bounds__(256) void k_out(
    const unsigned short* __restrict__ peh_ws, const int* __restrict__ mask,
    const float* __restrict__ ws, float* __restrict__ out)
{
  __shared__ float so[32][33];              // [j][32 n + pad]
  const int b  = blockIdx.x >> 10;          // 1024 blocks per batch (uniform)
  const int l  = threadIdx.x & 63;
  const int wv = threadIdx.x >> 6;
  const int c  = l & 31;
  const int h  = l >> 5;

  const unsigned* wa1h = (const unsigned*)ws + WS_WA1H + b*1024;
  const unsigned* wa2h = (const unsigned*)ws + WS_WA2H;
  uint4 A1[2][2], A2w[4];
  #pragma unroll
  for (int t = 0; t < 2; ++t)
    #pragma unroll
    for (int kc = 0; kc < 2; ++kc)
      A1[t][kc] = *(const uint4*)(wa1h + (c + 32*t)*16 + kc*8 + h*4);
  #pragma unroll
  for (int kc2 = 0; kc2 < 4; ++kc2)
    A2w[kc2] = *(const uint4*)(wa2h + (c*2 + h)*16 + kc2*4);

  const float* ba1f = ws + WS_BA1F + b*64;
  float bias1[2][16];
  #pragma unroll
  for (int t = 0; t < 2; ++t)
    #pragma unroll
    for (int r = 0; r < 16; ++r)
      bias1[t][r] = ba1f[(r&3) + 8*(r>>2) + 4*h + 32*t];

  // gamma-inverse addressing for pe_r at channel j=c
  const int hc  = (c >> 2) & 1;
  const int pc  = ((c >> 4) << 2) + (((c >> 3) & 1) << 1) + ((c >> 1) & 1);
  const int offc = hc*512 + pc*2 + (c & 1);     // u16 units within tile

  const int e0w = blockIdx.x*512 + wv*128;

  #pragma unroll
  for (int tt = 0; tt < 4; ++tt) {
    const int e0 = e0w + tt*32;
    const uint4* peb = (const uint4*)(peh_ws + (size_t)e0*32 + (size_t)(h*32 + c)*16);
    uint4 peB0 = peb[0];
    uint4 peB1 = peb[1];

    f16v acc1a, acc1b;
    #pragma unroll
    for (int r = 0; r < 16; ++r) { acc1a[r] = bias1[0][r]; acc1b[r] = bias1[1][r]; }
    acc1a = mfma16(A1[0][0], peB0, acc1a);
    acc1a = mfma16(A1[0][1], peB1, acc1a);
    acc1b = mfma16(A1[1][0], peB0, acc1b);
    acc1b = mfma16(A1[1][1], peB1, acc1b);

    // relu + pack -> GEMM2 A-frag chunks directly (delta-permuted Wa2 pairs slot-wise)
    unsigned u0[8], u1[8];
    #pragma unroll
    for (int p = 0; p < 8; ++p) {
      u0[p] = pkh(fmaxf(acc1a[2*p], 0.f), fmaxf(acc1a[2*p+1], 0.f));
      u1[p] = pkh(fmaxf(acc1b[2*p], 0.f), fmaxf(acc1b[2*p+1], 0.f));
    }

    f16v acc2;
    #pragma unroll
    for (int r = 0; r < 16; ++r) acc2[r] = 0.f;
    acc2 = mfma16(make_uint4(u0[0], u0[1], u0[2], u0[3]), A2w[0], acc2);
    acc2 = mfma16(make_uint4(u0[4], u0[5], u0[6], u0[7]), A2w[1], acc2);
    acc2 = mfma16(make_uint4(u1[0], u1[1], u1[2], u1[3]), A2w[2], acc2);
    acc2 = mfma16(make_uint4(u1[4], u1[5], u1[6], u1[7]), A2w[3], acc2);

    // mask -> finite -60 ; pe_r gathered via gamma-inverse addressing
    float v[16], pe_r[16];
    #pragma unroll
    for (int g = 0; g < 4; ++g) {
      int eb = 8*g + 4*h;
      int4 mm = *(const int4*)(mask + e0 + eb);
      v[4*g+0] = mm.x ? acc2[4*g+0] : MASK_NEG;
      v[4*g+1] = mm.y ? acc2[4*g+1] : MASK_NEG;
      v[4*g+2] = mm.z ? acc2[4*g+2] : MASK_NEG;
      v[4*g+3] = mm.w ? acc2[4*g+3] : MASK_NEG;
      #pragma unroll
      for (int i = 0; i < 4; ++i)
        pe_r[4*g+i] = (float)*(const _Float16*)(peh_ws + (size_t)e0*32 + offc + (eb + i)*16);
    }

    float sA = 0.f, wA = 0.f, sB = 0.f, wB = 0.f;
    #pragma unroll
    for (int r = 0; r < 8; ++r) {
      float pa = __expf(v[r]);
      float pb = __expf(v[r+8]);
      sA += pa; wA = fmaf(pa, pe_r[r],   wA);
      sB += pb; wB = fmaf(pb, pe_r[r+8], wB);
    }
    sA += __shfl_xor(sA, 32); wA += __shfl_xor(wA, 32);
    sB += __shfl_xor(sB, 32); wB += __shfl_xor(wB, 32);

    float num = h ? wB : wA;
    float den = h ? sB : sA;
    so[c][wv*8 + tt*2 + h] = __fdividef(num, den);
  }

  __syncthreads();
  // coalesced writes: thread t writes 16B of one output row (32 rows x 32 n)
  const int n0 = (blockIdx.x & 1023) * 32;
  const int r = threadIdx.x >> 3, uu = threadIdx.x & 7;
  float4* dst = (float4*)(out + (size_t)b*(DIM*NN) + (size_t)r*NN + n0 + uu*4);
  dst[0] = *(float4*)&so[r][uu*4];
}

extern "C" void kernel_launch(void* const* d_in, const int* in_sizes, int n_in,
                              void* d_out, int out_size, void* d_ws, size_t ws_size,
                              hipStream_t stream) {
  (void)in_sizes; (void)n_in; (void)out_size; (void)ws_size;
  const float* q_xyzs   = (const float*)d_in[0];
  const float* k_xyzs   = (const float*)d_in[1];
  const int*   knn_idx  = (const int*)d_in[2];
  const int*   mask     = (const int*)d_in[3];
  const float* pre_w1   = (const float*)d_in[4];
  const float* pre_b1   = (const float*)d_in[5];
  const float* pre_gn_w = (const float*)d_in[6];
  const float* pre_gn_b = (const float*)d_in[7];
  const float* pre_w2   = (const float*)d_in[8];
  const float* pre_b2   = (const float*)d_in[9];
  const float* attn_w1  = (const float*)d_in[10];
  const float* attn_b1  = (const float*)d_in[11];
  const float* attn_gn_w= (const float*)d_in[12];
  const float* attn_gn_b= (const float*)d_in[13];
  const float* attn_w2  = (const float*)d_in[14];
  float* ws  = (float*)d_ws;
  float* out = (float*)d_out;
  unsigned short* peh_ws = (unsigned short*)((char*)d_ws + PE_BYTE_OFF);

  hipMemsetAsync(ws, 0, (64 + 4*1056)*sizeof(float), stream);
  k_lpmom <<<dim3(NB*256+1), 256, 0, stream>>>(q_xyzs, k_xyzs, knn_idx, pre_w2, attn_w2, ws);
  k_fold1 <<<dim3(NB),        64, 0, stream>>>(pre_w1, pre_b1, pre_gn_w, pre_gn_b, ws);
  k_pe    <<<dim3(NB*256),   256, 0, stream>>>(q_xyzs, k_xyzs, knn_idx, pre_b2, ws, peh_ws);
  k_pemom <<<dim3(NB*128),   256, 0, stream>>>(peh_ws, ws);
  k_fold2m<<<dim3(NB),        64, 0, stream>>>(attn_w1, attn_b1, attn_gn_w, attn_gn_b, ws);
  k_out   <<<dim3(NB*1024),  256, 0, stream>>>(peh_ws, mask, ws, out);
}

// Round 13
// 199.059 us; speedup vs baseline: 1.1303x; 1.1303x over previous
//
#include <hip/hip_runtime.h>
#include <hip/hip_bf16.h>
#include <math.h>

#define NB 4
#define NN 32768
#define MM 32768
#define KK 16
#define HID 64
#define DIM 32
#define ENK (NN*KK)              // 524288 elements per batch (2^19)
#define EF  524288.0f
#define CNTG (16.0f*EF)
#define MASK_NEG (-60.0f)        // finite mask: exp(-60)=8.8e-27; all-masked row -> exact uniform

// ---- workspace u32/float offsets (small region) ----
#define WS_STATS1 0        // [4][16]  : slp[4], M10[10], pad
#define WS_STATS2 64       // [4][1056]: spe[32], Mpe[32*32]
#define WS_B1F    5312     // [4][64] f32
#define WS_WA1H   5568     // [4][64][16] u32 (half2 folded attn_w1, natural order)
#define WS_BA1F   9664     // [4][64] f32
#define WS_W2H    9920     // [32][32] u32 (half2 pre_w2, natural slot order)
#define WS_WA2H   10944    // [32][2][16] u32 (half2 attn_w2, delta-permuted per (j,h))
#define WS_W1H    11968    // [4][64][2] u32 (half2 folded pre_w1)
#define PE_BYTE_OFF 65536ull

typedef _Float16 h2v __attribute__((ext_vector_type(2)));
typedef _Float16 h8v __attribute__((ext_vector_type(8)));
typedef float f16v __attribute__((ext_vector_type(16)));

#if defined(__has_builtin)
#if __has_builtin(__builtin_amdgcn_fdot2)
#define USE_FDOT2 1
#endif
#endif
#ifndef USE_FDOT2
#define USE_FDOT2 0
#endif

__device__ __forceinline__ float dot2f(unsigned w, unsigned x, float acc) {
#if USE_FDOT2
  return __builtin_amdgcn_fdot2(__builtin_bit_cast(h2v, w),
                                __builtin_bit_cast(h2v, x), acc, false);
#else
  h2v a = __builtin_bit_cast(h2v, w);
  h2v b = __builtin_bit_cast(h2v, x);
  acc = fmaf((float)a[0], (float)b[0], acc);
  return fmaf((float)a[1], (float)b[1], acc);
#endif
}

__device__ __forceinline__ unsigned pkh(float a, float b) {
  return __builtin_bit_cast(unsigned, __builtin_amdgcn_cvt_pkrtz(a, b));
}

__device__ __forceinline__ f16v mfma16(uint4 a, uint4 b, f16v c) {
  return __builtin_amdgcn_mfma_f32_32x32x16_f16(
      __builtin_bit_cast(h8v, a), __builtin_bit_cast(h8v, b), c, 0, 0, 0);
}

template<int NV>
__device__ __forceinline__ void block_reduce_atomic(float* v, float* dst) {
  #pragma unroll
  for (int i = 0; i < NV; ++i) {
    float x = v[i];
    x += __shfl_down(x, 32);
    x += __shfl_down(x, 16);
    x += __shfl_down(x, 8);
    x += __shfl_down(x, 4);
    x += __shfl_down(x, 2);
    x += __shfl_down(x, 1);
    v[i] = x;
  }
  __shared__ float red[4][NV];
  const int lane = threadIdx.x & 63;
  const int wv = threadIdx.x >> 6;
  if (lane == 0) {
    #pragma unroll
    for (int i = 0; i < NV; ++i) red[wv][i] = v[i];
  }
  __syncthreads();
  if (threadIdx.x < NV) {
    float t = red[0][threadIdx.x] + red[1][threadIdx.x] +
              red[2][threadIdx.x] + red[3][threadIdx.x];
    atomicAdd(dst + threadIdx.x, t);
  }
}

__device__ __forceinline__ void compute_lp(const float* __restrict__ qb,
                                           const float* __restrict__ kb,
                                           int n, int idx,
                                           float& lp0, float& lp1, float& lp2, float& lp3) {
  float dx = kb[idx]        - qb[n];
  float dy = kb[MM + idx]   - qb[NN + n];
  float dz = kb[2*MM + idx] - qb[2*NN + n];
  float dist = sqrtf(fmaf(dx, dx, fmaf(dy, dy, dz*dz)));
  float inv = 1.0f / fmaxf(dist, 1e-12f);
  lp0 = dx * inv; lp1 = dy * inv; lp2 = dz * inv; lp3 = dist;
}

// ---------------- Pass A: lp moments (grid NB*256 + 1; last block packs weights) ----------------
__global__ __launch_bounds__(256) void k_lpmom(
    const float* __restrict__ q_xyzs, const float* __restrict__ k_xyzs,
    const int* __restrict__ knn_idx,
    const float* __restrict__ w2, const float* __restrict__ wa2,
    float* __restrict__ ws)
{
  if (blockIdx.x == NB*256) {                 // weight-pack block
    int t = threadIdx.x;
    unsigned* wsu = (unsigned*)ws;
    if (t < 32) {
      const float* src = w2 + t*64;
      unsigned* dst = wsu + WS_W2H + t*32;
      #pragma unroll
      for (int i = 0; i < 32; ++i) dst[i] = pkh(src[2*i], src[2*i+1]);
    } else if (t >= 64 && t < 128) {
      // attn_w2 delta-permuted pack: slot (j, h, kc2, pb) = Wa2[j][delta], delta pairs (base,base+1)
      int j  = (t - 64) & 31;
      int hh = (t - 64) >> 5;
      const float* src = wa2 + j*64;
      unsigned* dst = wsu + WS_WA2H + (j*2 + hh)*16;
      #pragma unroll
      for (int kc2 = 0; kc2 < 4; ++kc2)
        #pragma unroll
        for (int pb = 0; pb < 4; ++pb) {
          int base = 32*(kc2>>1) + 16*(kc2&1) + 8*(pb>>1) + 4*hh + 2*(pb&1);
          dst[kc2*4 + pb] = pkh(src[base], src[base+1]);
        }
    }
    return;
  }
  const int b   = blockIdx.x >> 8;
  const int blk = blockIdx.x & 255;
  const float* qb = q_xyzs + b*3*NN;
  const float* kb = k_xyzs + b*3*MM;
  const int* idxb = knn_idx + b*ENK;

  float a[14];
  #pragma unroll
  for (int i = 0; i < 14; ++i) a[i] = 0.f;

  for (int it = 0; it < 8; ++it) {
    int el = (blk*8 + it)*256 + threadIdx.x;
    int n = el >> 4;
    int idx = idxb[el];
    float lp0, lp1, lp2, lp3;
    compute_lp(qb, kb, n, idx, lp0, lp1, lp2, lp3);
    a[0] += lp0; a[1] += lp1; a[2] += lp2; a[3] += lp3;
    a[4] = fmaf(lp0, lp0, a[4]);  a[5] = fmaf(lp0, lp1, a[5]);
    a[6] = fmaf(lp0, lp2, a[6]);  a[7] = fmaf(lp0, lp3, a[7]);
    a[8] = fmaf(lp1, lp1, a[8]);  a[9] = fmaf(lp1, lp2, a[9]);
    a[10] = fmaf(lp1, lp3, a[10]); a[11] = fmaf(lp2, lp2, a[11]);
    a[12] = fmaf(lp2, lp3, a[12]); a[13] = fmaf(lp3, lp3, a[13]);
  }
  block_reduce_atomic<14>(a, ws + WS_STATS1 + b*16);
}

// ---------------- Fold GN1 into W1 (writes half2-packed + f32 bias) ----------------
__global__ __launch_bounds__(64) void k_fold1(
    const float* __restrict__ w1, const float* __restrict__ b1,
    const float* __restrict__ gw, const float* __restrict__ gb,
    float* __restrict__ ws)
{
  int b = blockIdx.x, o = threadIdx.x;
  const float* st = ws + WS_STATS1 + b*16;
  float4 w = ((const float4*)w1)[o];
  float bb = b1[o];
  float dot = w.x*st[0] + w.y*st[1] + w.z*st[2] + w.w*st[3];
  float quad = w.x*w.x*st[4] + w.y*w.y*st[8] + w.z*w.z*st[11] + w.w*w.w*st[13]
    + 2.f*(w.x*w.y*st[5] + w.x*w.z*st[6] + w.x*w.w*st[7]
         + w.y*w.z*st[9] + w.y*w.w*st[10] + w.z*w.w*st[12]);
  float sum = dot + EF*bb;
  float ssq = quad + 2.f*bb*dot + EF*bb*bb;
  #pragma unroll
  for (int m = 1; m < 16; m <<= 1) {
    sum += __shfl_xor(sum, m);
    ssq += __shfl_xor(ssq, m);
  }
  float mu  = sum / CNTG;
  float var = ssq / CNTG - mu*mu;
  float sc  = rsqrtf(var + 1e-5f) * gw[o];
  unsigned* w1hd = (unsigned*)ws + WS_W1H + b*128;
  w1hd[o*2]   = pkh(w.x*sc, w.y*sc);
  w1hd[o*2+1] = pkh(w.z*sc, w.w*sc);
  (ws + WS_B1F)[b*64 + o] = (bb - mu)*sc + gb[o];
}

// ---------------- Pass B (MFMA): gather -> h1 -> pe = W2 h1 + b2, store f16 element-major ----------------
__global__ __launch_bounds__(256) void k_pe(
    const float* __restrict__ q_xyzs, const float* __restrict__ k_xyzs,
    const int* __restrict__ knn_idx, const float* __restrict__ b2,
    const float* __restrict__ ws, unsigned short* __restrict__ peh_ws)
{
  const int b  = blockIdx.x >> 8;           // 256 blocks per batch (uniform)
  const int l  = threadIdx.x & 63;
  const int wv = threadIdx.x >> 6;
  const int c  = l & 31;
  const int h  = l >> 5;
  const float* qb = q_xyzs + b*3*NN;
  const float* kb = k_xyzs + b*3*MM;

  const unsigned* w1h = (const unsigned*)ws + WS_W1H + b*128;
  const float* b1f = ws + WS_B1F + b*64;
  unsigned w01[32], w23[32];
  float bch[32];
  #pragma unroll
  for (int kc = 0; kc < 4; ++kc)
    #pragma unroll
    for (int jj = 0; jj < 8; ++jj) {
      int ch = kc*16 + h*8 + jj;
      w01[kc*8+jj] = w1h[ch*2];
      w23[kc*8+jj] = w1h[ch*2+1];
      bch[kc*8+jj] = b1f[ch];
    }
  const unsigned* w2h = (const unsigned*)ws + WS_W2H;
  uint4 A2[4];
  #pragma unroll
  for (int kc = 0; kc < 4; ++kc)
    A2[kc] = *(const uint4*)(w2h + c*32 + kc*8 + h*4);
  float bias2[16];
  #pragma unroll
  for (int r = 0; r < 16; ++r) bias2[r] = b2[(r&3) + 8*(r>>2) + 4*h];

  const int e0w = blockIdx.x*2048 + wv*512;

  // prefetch tile 0's gather
  int idx0 = knn_idx[e0w + c];
  float gxn = kb[idx0], gyn = kb[MM + idx0], gzn = kb[2*MM + idx0];

  #pragma unroll 1
  for (int tt = 0; tt < 16; ++tt) {
    const int e = e0w + tt*32 + c;
    int n = (e & (ENK-1)) >> 4;
    float gx = gxn, gy = gyn, gz = gzn;
    if (tt < 15) {
      int idn = knn_idx[e + 32];
      gxn = kb[idn]; gyn = kb[MM + idn]; gzn = kb[2*MM + idn];
    }
    float dx = gx - qb[n];
    float dy = gy - qb[NN + n];
    float dz = gz - qb[2*NN + n];
    float dist = sqrtf(fmaf(dx, dx, fmaf(dy, dy, dz*dz)));
    float inv = 1.0f / fmaxf(dist, 1e-12f);
    unsigned lp01 = pkh(dx*inv, dy*inv), lp23 = pkh(dz*inv, dist);

    uint4 Bf[4];
    #pragma unroll
    for (int kc = 0; kc < 4; ++kc) {
      unsigned bb[4];
      #pragma unroll
      for (int q = 0; q < 4; ++q) {
        int i0 = kc*8 + 2*q, i1 = i0 + 1;
        float xa = fmaxf(dot2f(w01[i0], lp01, dot2f(w23[i0], lp23, bch[i0])), 0.f);
        float xb = fmaxf(dot2f(w01[i1], lp01, dot2f(w23[i1], lp23, bch[i1])), 0.f);
        bb[q] = pkh(xa, xb);
      }
      Bf[kc] = make_uint4(bb[0], bb[1], bb[2], bb[3]);
    }

    f16v acc;
    #pragma unroll
    for (int r = 0; r < 16; ++r) acc[r] = bias2[r];
    #pragma unroll
    for (int kc = 0; kc < 4; ++kc) acc = mfma16(A2[kc], Bf[kc], acc);

    // pack row pairs, shfl cross-half, assemble element-major, store
    unsigned u[8], x[8];
    #pragma unroll
    for (int p = 0; p < 8; ++p) u[p] = pkh(acc[2*p], acc[2*p+1]);
    #pragma unroll
    for (int p = 0; p < 8; ++p) x[p] = __shfl_xor(u[p], 32);
    uint4 f0, f1;
    f0.x = h ? x[4] : u[0];  f0.y = h ? x[5] : u[1];
    f0.z = h ? u[4] : x[0];  f0.w = h ? u[5] : x[1];
    f1.x = h ? x[6] : u[2];  f1.y = h ? x[7] : u[3];
    f1.z = h ? u[6] : x[2];  f1.w = h ? u[7] : x[3];
    uint4* d = (uint4*)(peh_ws + (size_t)e*32 + h*16);
    d[0] = f0;
    d[1] = f1;
  }
}

// ---------------- Pass B2: pe moments via MFMA (M = pe^T pe, spe = sum pe) ----------------
__global__ __launch_bounds__(256) void k_pemom(
    const unsigned short* __restrict__ peh_ws, float* __restrict__ ws)
{
  const int b   = blockIdx.x >> 7;          // 128 blocks per batch
  const int blk = blockIdx.x & 127;
  const int wv  = threadIdx.x >> 6;
  const int l   = threadIdx.x & 63;
  const int c   = l & 31;
  const int h   = l >> 5;

  const size_t ebase = (size_t)b*ENK + ((size_t)(blk*4 + wv))*1024;
  const unsigned short* pbase = peh_ws + ebase*32 + (size_t)h*8*32 + c;

  f16v acc;
  #pragma unroll
  for (int i = 0; i < 16; ++i) acc[i] = 0.f;
  float spe = 0.f;
  const unsigned ONE = pkh(1.f, 1.f);

  for (int t = 0; t < 64; ++t) {
    const unsigned short* p = pbase + (size_t)t*16*32;
    unsigned u0 = (unsigned)p[0*32]  | ((unsigned)p[1*32] << 16);
    unsigned u1 = (unsigned)p[2*32]  | ((unsigned)p[3*32] << 16);
    unsigned u2 = (unsigned)p[4*32]  | ((unsigned)p[5*32] << 16);
    unsigned u3 = (unsigned)p[6*32]  | ((unsigned)p[7*32] << 16);
    uint4 uu = make_uint4(u0, u1, u2, u3);
    h8v frag = __builtin_bit_cast(h8v, uu);
    acc = __builtin_amdgcn_mfma_f32_32x32x16_f16(frag, frag, acc, 0, 0, 0);
    spe = dot2f(u0, ONE, spe);
    spe = dot2f(u1, ONE, spe);
    spe = dot2f(u2, ONE, spe);
    spe = dot2f(u3, ONE, spe);
  }

  float* st2 = ws + WS_STATS2 + b*1056;
  spe += __shfl_down(spe, 32);
  if (l < 32) atomicAdd(st2 + c, spe);
  #pragma unroll
  for (int r = 0; r < 16; ++r) {
    int row = (r & 3) + 8*(r >> 2) + 4*h;
    atomicAdd(st2 + 32 + row*32 + c, acc[r]);
  }
}

// ---------------- Fold GN2 into Wa1, write half2-packed (natural order) ----------------
__global__ __launch_bounds__(64) void k_fold2m(
    const float* __restrict__ wa1, const float* __restrict__ ba1,
    const float* __restrict__ gw2, const float* __restrict__ gb2,
    float* __restrict__ ws)
{
  int b = blockIdx.x, o = threadIdx.x;
  const float* st = ws + WS_STATS2 + b*1056;
  float w[32];
  const float4* wrow = (const float4*)wa1 + o*8;
  #pragma unroll
  for (int i = 0; i < 8; ++i) {
    float4 t = wrow[i];
    w[4*i] = t.x; w[4*i+1] = t.y; w[4*i+2] = t.z; w[4*i+3] = t.w;
  }
  float dot = 0.f;
  #pragma unroll
  for (int cc = 0; cc < 32; ++cc) dot = fmaf(w[cc], st[cc], dot);
  float quad = 0.f;
  #pragma unroll
  for (int rr = 0; rr < 32; ++rr) {
    const float* Mr = st + 32 + rr*32;
    float mr = 0.f;
    #pragma unroll
    for (int cc = 0; cc < 32; ++cc) mr = fmaf(Mr[cc], w[cc], mr);
    quad = fmaf(w[rr], mr, quad);
  }
  float bb = ba1[o];
  float sum = dot + EF*bb;
  float ssq = quad + 2.f*bb*dot + EF*bb*bb;
  #pragma unroll
  for (int m = 1; m < 16; m <<= 1) {
    sum += __shfl_xor(sum, m);
    ssq += __shfl_xor(ssq, m);
  }
  float mu  = sum / CNTG;
  float var = ssq / CNTG - mu*mu;
  float sc  = rsqrtf(var + 1e-5f) * gw2[o];
  unsigned* dst = (unsigned*)ws + WS_WA1H + (b*64 + o)*16;
  #pragma unroll
  for (int i2 = 0; i2 < 16; ++i2) dst[i2] = pkh(w[2*i2]*sc, w[2*i2+1]*sc);
  (ws + WS_BA1F)[b*64 + o] = (bb - mu)*sc + gb2[o];
}

// ---------------- Pass C (MFMA): GEMM1 -> (no exchange) GEMM2 via delta-permuted Wa2 ----------------
__global__ __launch_bounds__(256) void k_out(
    const unsigned short* __restrict__ peh_ws, const int* __restrict__ mask,
    const float* __restrict__ ws, float* __restrict__ out)
{
  __shared__ float so[32][33];              // [j][32 n + pad]
  const int b  = blockIdx.x >> 10;          // 1024 blocks per batch (uniform)
  const int l  = threadIdx.x & 63;
  const int wv = threadIdx.x >> 6;
  const int c  = l & 31;
  const int h  = l >> 5;

  const unsigned* wa1h = (const unsigned*)ws + WS_WA1H + b*1024;
  const unsigned* wa2h = (const unsigned*)ws + WS_WA2H;
  uint4 A1[2][2], A2w[4];
  #pragma unroll
  for (int t = 0; t < 2; ++t)
    #pragma unroll
    for (int kc = 0; kc < 2; ++kc)
      A1[t][kc] = *(const uint4*)(wa1h + (c + 32*t)*16 + kc*8 + h*4);
  #pragma unroll
  for (int kc2 = 0; kc2 < 4; ++kc2)
    A2w[kc2] = *(const uint4*)(wa2h + (c*2 + h)*16 + kc2*4);

  const float* ba1f = ws + WS_BA1F + b*64;
  float bias1[2][16];
  #pragma unroll
  for (int t = 0; t < 2; ++t)
    #pragma unroll
    for (int r = 0; r < 16; ++r)
      bias1[t][r] = ba1f[(r&3) + 8*(r>>2) + 4*h + 32*t];

  const int e0w = blockIdx.x*512 + wv*128;

  #pragma unroll
  for (int tt = 0; tt < 4; ++tt) {
    const int e0 = e0w + tt*32;
    const unsigned short* peb = peh_ws + (size_t)(e0 + c)*32 + h*8;
    uint4 peB0 = *(const uint4*)peb;
    uint4 peB1 = *(const uint4*)(peb + 16);

    f16v acc1a, acc1b;
    #pragma unroll
    for (int r = 0; r < 16; ++r) { acc1a[r] = bias1[0][r]; acc1b[r] = bias1[1][r]; }
    acc1a = mfma16(A1[0][0], peB0, acc1a);
    acc1a = mfma16(A1[0][1], peB1, acc1a);
    acc1b = mfma16(A1[1][0], peB0, acc1b);
    acc1b = mfma16(A1[1][1], peB1, acc1b);

    // relu + pack -> GEMM2 A-frags directly (delta-permuted Wa2 pairs slot-wise; no exchange)
    unsigned u0[8], u1[8];
    #pragma unroll
    for (int p = 0; p < 8; ++p) {
      u0[p] = pkh(fmaxf(acc1a[2*p], 0.f), fmaxf(acc1a[2*p+1], 0.f));
      u1[p] = pkh(fmaxf(acc1b[2*p], 0.f), fmaxf(acc1b[2*p+1], 0.f));
    }

    f16v acc2;
    #pragma unroll
    for (int r = 0; r < 16; ++r) acc2[r] = 0.f;
    acc2 = mfma16(make_uint4(u0[0], u0[1], u0[2], u0[3]), A2w[0], acc2);
    acc2 = mfma16(make_uint4(u0[4], u0[5], u0[6], u0[7]), A2w[1], acc2);
    acc2 = mfma16(make_uint4(u1[0], u1[1], u1[2], u1[3]), A2w[2], acc2);
    acc2 = mfma16(make_uint4(u1[4], u1[5], u1[6], u1[7]), A2w[3], acc2);

    // mask -> finite -60 ; pe_r coalesced element-major loads
    float v[16], pe_r[16];
    #pragma unroll
    for (int g = 0; g < 4; ++g) {
      int eb = 8*g + 4*h;
      int4 mm = *(const int4*)(mask + e0 + eb);
      v[4*g+0] = mm.x ? acc2[4*g+0] : MASK_NEG;
      v[4*g+1] = mm.y ? acc2[4*g+1] : MASK_NEG;
      v[4*g+2] = mm.z ? acc2[4*g+2] : MASK_NEG;
      v[4*g+3] = mm.w ? acc2[4*g+3] : MASK_NEG;
      #pragma unroll
      for (int i = 0; i < 4; ++i)
        pe_r[4*g+i] = (float)*(const _Float16*)(peh_ws + (size_t)(e0 + eb + i)*32 + c);
    }

    float sA = 0.f, wA = 0.f, sB = 0.f, wB = 0.f;
    #pragma unroll
    for (int r = 0; r < 8; ++r) {
      float pa = __expf(v[r]);
      float pb = __expf(v[r+8]);
      sA += pa; wA = fmaf(pa, pe_r[r],   wA);
      sB += pb; wB = fmaf(pb, pe_r[r+8], wB);
    }
    sA += __shfl_xor(sA, 32); wA += __shfl_xor(wA, 32);
    sB += __shfl_xor(sB, 32); wB += __shfl_xor(wB, 32);

    float num = h ? wB : wA;
    float den = h ? sB : sA;
    so[c][wv*8 + tt*2 + h] = __fdividef(num, den);
  }

  __syncthreads();
  // coalesced writes: thread t writes 16B of one output row (32 rows x 32 n)
  const int n0 = (blockIdx.x & 1023) * 32;
  const int r = threadIdx.x >> 3, uu = threadIdx.x & 7;
  float4* dst = (float4*)(out + (size_t)b*(DIM*NN) + (size_t)r*NN + n0 + uu*4);
  dst[0] = *(float4*)&so[r][uu*4];
}

extern "C" void kernel_launch(void* const* d_in, const int* in_sizes, int n_in,
                              void* d_out, int out_size, void* d_ws, size_t ws_size,
                              hipStream_t stream) {
  (void)in_sizes; (void)n_in; (void)out_size; (void)ws_size;
  const float* q_xyzs   = (const float*)d_in[0];
  const float* k_xyzs   = (const float*)d_in[1];
  const int*   knn_idx  = (const int*)d_in[2];
  const int*   mask     = (const int*)d_in[3];
  const float* pre_w1   = (const float*)d_in[4];
  const float* pre_b1   = (const float*)d_in[5];
  const float* pre_gn_w = (const float*)d_in[6];
  const float* pre_gn_b = (const float*)d_in[7];
  const float* pre_w2   = (const float*)d_in[8];
  const float* pre_b2   = (const float*)d_in[9];
  const float* attn_w1  = (const float*)d_in[10];
  const float* attn_b1  = (const float*)d_in[11];
  const float* attn_gn_w= (const float*)d_in[12];
  const float* attn_gn_b= (const float*)d_in[13];
  const float* attn_w2  = (const float*)d_in[14];
  float* ws  = (float*)d_ws;
  float* out = (float*)d_out;
  unsigned short* peh_ws = (unsigned short*)((char*)d_ws + PE_BYTE_OFF);

  hipMemsetAsync(ws, 0, (64 + 4*1056)*sizeof(float), stream);
  k_lpmom <<<dim3(NB*256+1), 256, 0, stream>>>(q_xyzs, k_xyzs, knn_idx, pre_w2, attn_w2, ws);
  k_fold1 <<<dim3(NB),        64, 0, stream>>>(pre_w1, pre_b1, pre_gn_w, pre_gn_b, ws);
  k_pe    <<<dim3(NB*256),   256, 0, stream>>>(q_xyzs, k_xyzs, knn_idx, pre_b2, ws, peh_ws);
  k_pemom <<<dim3(NB*128),   256, 0, stream>>>(peh_ws, ws);
  k_fold2m<<<dim3(NB),        64, 0, stream>>>(attn_w1, attn_b1, attn_gn_w, attn_gn_b, ws);
  k_out   <<<dim3(NB*1024),  256, 0, stream>>>(peh_ws, mask, ws, out);
}

// Round 14
// 189.711 us; speedup vs baseline: 1.1860x; 1.0493x over previous
//
#include <hip/hip_runtime.h>
#include <hip/hip_bf16.h>
#include <math.h>

#define NB 4
#define NN 32768
#define MM 32768
#define KK 16
#define HID 64
#define DIM 32
#define ENK (NN*KK)              // 524288 elements per batch (2^19)
#define EF  524288.0f
#define CNTG (16.0f*EF)
#define MASK_NEG (-60.0f)        // finite mask: exp(-60)=8.8e-27; all-masked row -> exact uniform

// ---- workspace u32/float offsets (small region) ----
#define WS_STATS1 0        // [4][16]  : slp[4], M10[10], pad
#define WS_STATS2 64       // [4][1056]: spe[32], Mpe[32*32]
#define WS_B1F    5312     // [4][64] f32
#define WS_WA1H   5568     // [4][64][16] u32 (half2 folded attn_w1, natural order)
#define WS_BA1F   9664     // [4][64] f32
#define WS_W2H    9920     // [32][32] u32 (half2 pre_w2, natural slot order)
#define WS_WA2H   10944    // [32][2][16] u32 (half2 attn_w2, delta-permuted per (j,h))
#define WS_W1H    11968    // [4][64][2] u32 (half2 folded pre_w1)
#define PE_BYTE_OFF 65536ull

typedef _Float16 h2v __attribute__((ext_vector_type(2)));
typedef _Float16 h8v __attribute__((ext_vector_type(8)));
typedef float f16v __attribute__((ext_vector_type(16)));

#if defined(__has_builtin)
#if __has_builtin(__builtin_amdgcn_fdot2)
#define USE_FDOT2 1
#endif
#endif
#ifndef USE_FDOT2
#define USE_FDOT2 0
#endif

__device__ __forceinline__ float dot2f(unsigned w, unsigned x, float acc) {
#if USE_FDOT2
  return __builtin_amdgcn_fdot2(__builtin_bit_cast(h2v, w),
                                __builtin_bit_cast(h2v, x), acc, false);
#else
  h2v a = __builtin_bit_cast(h2v, w);
  h2v b = __builtin_bit_cast(h2v, x);
  acc = fmaf((float)a[0], (float)b[0], acc);
  return fmaf((float)a[1], (float)b[1], acc);
#endif
}

__device__ __forceinline__ unsigned pkh(float a, float b) {
  return __builtin_bit_cast(unsigned, __builtin_amdgcn_cvt_pkrtz(a, b));
}

__device__ __forceinline__ f16v mfma16(uint4 a, uint4 b, f16v c) {
  return __builtin_amdgcn_mfma_f32_32x32x16_f16(
      __builtin_bit_cast(h8v, a), __builtin_bit_cast(h8v, b), c, 0, 0, 0);
}

template<int NV>
__device__ __forceinline__ void block_reduce_atomic(float* v, float* dst) {
  #pragma unroll
  for (int i = 0; i < NV; ++i) {
    float x = v[i];
    x += __shfl_down(x, 32);
    x += __shfl_down(x, 16);
    x += __shfl_down(x, 8);
    x += __shfl_down(x, 4);
    x += __shfl_down(x, 2);
    x += __shfl_down(x, 1);
    v[i] = x;
  }
  __shared__ float red[4][NV];
  const int lane = threadIdx.x & 63;
  const int wv = threadIdx.x >> 6;
  if (lane == 0) {
    #pragma unroll
    for (int i = 0; i < NV; ++i) red[wv][i] = v[i];
  }
  __syncthreads();
  if (threadIdx.x < NV) {
    float t = red[0][threadIdx.x] + red[1][threadIdx.x] +
              red[2][threadIdx.x] + red[3][threadIdx.x];
    atomicAdd(dst + threadIdx.x, t);
  }
}

__device__ __forceinline__ void compute_lp(const float* __restrict__ qb,
                                           const float* __restrict__ kb,
                                           int n, int idx,
                                           float& lp0, float& lp1, float& lp2, float& lp3) {
  float dx = kb[idx]        - qb[n];
  float dy = kb[MM + idx]   - qb[NN + n];
  float dz = kb[2*MM + idx] - qb[2*NN + n];
  float dist = sqrtf(fmaf(dx, dx, fmaf(dy, dy, dz*dz)));
  float inv = 1.0f / fmaxf(dist, 1e-12f);
  lp0 = dx * inv; lp1 = dy * inv; lp2 = dz * inv; lp3 = dist;
}

// ---------------- Pass A: lp moments (grid NB*256 + 1; last block packs weights) ----------------
__global__ __launch_bounds__(256) void k_lpmom(
    const float* __restrict__ q_xyzs, const float* __restrict__ k_xyzs,
    const int* __restrict__ knn_idx,
    const float* __restrict__ w2, const float* __restrict__ wa2,
    float* __restrict__ ws)
{
  if (blockIdx.x == NB*256) {                 // weight-pack block
    int t = threadIdx.x;
    unsigned* wsu = (unsigned*)ws;
    if (t < 32) {
      const float* src = w2 + t*64;
      unsigned* dst = wsu + WS_W2H + t*32;
      #pragma unroll
      for (int i = 0; i < 32; ++i) dst[i] = pkh(src[2*i], src[2*i+1]);
    } else if (t >= 64 && t < 128) {
      // attn_w2 delta-permuted pack: slot (j, h, kc2, pb) = Wa2[j][delta], delta pairs (base,base+1)
      int j  = (t - 64) & 31;
      int hh = (t - 64) >> 5;
      const float* src = wa2 + j*64;
      unsigned* dst = wsu + WS_WA2H + (j*2 + hh)*16;
      #pragma unroll
      for (int kc2 = 0; kc2 < 4; ++kc2)
        #pragma unroll
        for (int pb = 0; pb < 4; ++pb) {
          int base = 32*(kc2>>1) + 16*(kc2&1) + 8*(pb>>1) + 4*hh + 2*(pb&1);
          dst[kc2*4 + pb] = pkh(src[base], src[base+1]);
        }
    }
    return;
  }
  const int b   = blockIdx.x >> 8;
  const int blk = blockIdx.x & 255;
  const float* qb = q_xyzs + b*3*NN;
  const float* kb = k_xyzs + b*3*MM;
  const int* idxb = knn_idx + b*ENK;

  float a[14];
  #pragma unroll
  for (int i = 0; i < 14; ++i) a[i] = 0.f;

  #pragma unroll
  for (int it = 0; it < 8; ++it) {
    int el = (blk*8 + it)*256 + threadIdx.x;
    int n = el >> 4;
    int idx = idxb[el];
    float lp0, lp1, lp2, lp3;
    compute_lp(qb, kb, n, idx, lp0, lp1, lp2, lp3);
    a[0] += lp0; a[1] += lp1; a[2] += lp2; a[3] += lp3;
    a[4] = fmaf(lp0, lp0, a[4]);  a[5] = fmaf(lp0, lp1, a[5]);
    a[6] = fmaf(lp0, lp2, a[6]);  a[7] = fmaf(lp0, lp3, a[7]);
    a[8] = fmaf(lp1, lp1, a[8]);  a[9] = fmaf(lp1, lp2, a[9]);
    a[10] = fmaf(lp1, lp3, a[10]); a[11] = fmaf(lp2, lp2, a[11]);
    a[12] = fmaf(lp2, lp3, a[12]); a[13] = fmaf(lp3, lp3, a[13]);
  }
  block_reduce_atomic<14>(a, ws + WS_STATS1 + b*16);
}

// ---------------- Fold GN1 into W1 (writes half2-packed + f32 bias) ----------------
__global__ __launch_bounds__(64) void k_fold1(
    const float* __restrict__ w1, const float* __restrict__ b1,
    const float* __restrict__ gw, const float* __restrict__ gb,
    float* __restrict__ ws)
{
  int b = blockIdx.x, o = threadIdx.x;
  const float* st = ws + WS_STATS1 + b*16;
  float4 w = ((const float4*)w1)[o];
  float bb = b1[o];
  float dot = w.x*st[0] + w.y*st[1] + w.z*st[2] + w.w*st[3];
  float quad = w.x*w.x*st[4] + w.y*w.y*st[8] + w.z*w.z*st[11] + w.w*w.w*st[13]
    + 2.f*(w.x*w.y*st[5] + w.x*w.z*st[6] + w.x*w.w*st[7]
         + w.y*w.z*st[9] + w.y*w.w*st[10] + w.z*w.w*st[12]);
  float sum = dot + EF*bb;
  float ssq = quad + 2.f*bb*dot + EF*bb*bb;
  #pragma unroll
  for (int m = 1; m < 16; m <<= 1) {
    sum += __shfl_xor(sum, m);
    ssq += __shfl_xor(ssq, m);
  }
  float mu  = sum / CNTG;
  float var = ssq / CNTG - mu*mu;
  float sc  = rsqrtf(var + 1e-5f) * gw[o];
  unsigned* w1hd = (unsigned*)ws + WS_W1H + b*128;
  w1hd[o*2]   = pkh(w.x*sc, w.y*sc);
  w1hd[o*2+1] = pkh(w.z*sc, w.w*sc);
  (ws + WS_B1F)[b*64 + o] = (bb - mu)*sc + gb[o];
}

// ---------------- Pass B (MFMA): gather -> h1 -> pe = W2 h1 + b2, store f16 element-major ----------------
// grid NB*256, 16 tiles of 32 per wave; unroll-2 gives 2 gather chains in flight.
__global__ __launch_bounds__(256) void k_pe(
    const float* __restrict__ q_xyzs, const float* __restrict__ k_xyzs,
    const int* __restrict__ knn_idx, const float* __restrict__ b2,
    const float* __restrict__ ws, unsigned short* __restrict__ peh_ws)
{
  const int b  = blockIdx.x >> 8;           // 256 blocks per batch (uniform)
  const int l  = threadIdx.x & 63;
  const int wv = threadIdx.x >> 6;
  const int c  = l & 31;
  const int h  = l >> 5;
  const float* qb = q_xyzs + b*3*NN;
  const float* kb = k_xyzs + b*3*MM;

  const unsigned* w1h = (const unsigned*)ws + WS_W1H + b*128;
  const float* b1f = ws + WS_B1F + b*64;
  unsigned w01[32], w23[32];
  float bch[32];
  #pragma unroll
  for (int kc = 0; kc < 4; ++kc)
    #pragma unroll
    for (int jj = 0; jj < 8; ++jj) {
      int ch = kc*16 + h*8 + jj;
      w01[kc*8+jj] = w1h[ch*2];
      w23[kc*8+jj] = w1h[ch*2+1];
      bch[kc*8+jj] = b1f[ch];
    }
  const unsigned* w2h = (const unsigned*)ws + WS_W2H;
  uint4 A2[4];
  #pragma unroll
  for (int kc = 0; kc < 4; ++kc)
    A2[kc] = *(const uint4*)(w2h + c*32 + kc*8 + h*4);
  float bias2[16];
  #pragma unroll
  for (int r = 0; r < 16; ++r) bias2[r] = b2[(r&3) + 8*(r>>2) + 4*h];

  const int e0w = blockIdx.x*2048 + wv*512;

  #pragma unroll 2
  for (int tt = 0; tt < 16; ++tt) {
    const int e = e0w + tt*32 + c;
    int n = (e & (ENK-1)) >> 4;
    int idx = knn_idx[e];
    float lp0, lp1, lp2, lp3;
    compute_lp(qb, kb, n, idx, lp0, lp1, lp2, lp3);
    unsigned lp01 = pkh(lp0, lp1), lp23 = pkh(lp2, lp3);

    uint4 Bf[4];
    #pragma unroll
    for (int kc = 0; kc < 4; ++kc) {
      unsigned bb[4];
      #pragma unroll
      for (int q = 0; q < 4; ++q) {
        int i0 = kc*8 + 2*q, i1 = i0 + 1;
        float xa = fmaxf(dot2f(w01[i0], lp01, dot2f(w23[i0], lp23, bch[i0])), 0.f);
        float xb = fmaxf(dot2f(w01[i1], lp01, dot2f(w23[i1], lp23, bch[i1])), 0.f);
        bb[q] = pkh(xa, xb);
      }
      Bf[kc] = make_uint4(bb[0], bb[1], bb[2], bb[3]);
    }

    f16v acc;
    #pragma unroll
    for (int r = 0; r < 16; ++r) acc[r] = bias2[r];
    #pragma unroll
    for (int kc = 0; kc < 4; ++kc) acc = mfma16(A2[kc], Bf[kc], acc);

    // pack row pairs, shfl cross-half, assemble element-major, store
    unsigned u[8], x[8];
    #pragma unroll
    for (int p = 0; p < 8; ++p) u[p] = pkh(acc[2*p], acc[2*p+1]);
    #pragma unroll
    for (int p = 0; p < 8; ++p) x[p] = __shfl_xor(u[p], 32);
    uint4 f0, f1;
    f0.x = h ? x[4] : u[0];  f0.y = h ? x[5] : u[1];
    f0.z = h ? u[4] : x[0];  f0.w = h ? u[5] : x[1];
    f1.x = h ? x[6] : u[2];  f1.y = h ? x[7] : u[3];
    f1.z = h ? u[6] : x[2];  f1.w = h ? u[7] : x[3];
    uint4* d = (uint4*)(peh_ws + (size_t)e*32 + h*16);
    d[0] = f0;
    d[1] = f1;
  }
}

// ---------------- Pass B2: pe moments via MFMA (M = pe^T pe, spe = sum pe) ----------------
__global__ __launch_bounds__(256) void k_pemom(
    const unsigned short* __restrict__ peh_ws, float* __restrict__ ws)
{
  const int b   = blockIdx.x >> 7;          // 128 blocks per batch
  const int blk = blockIdx.x & 127;
  const int wv  = threadIdx.x >> 6;
  const int l   = threadIdx.x & 63;
  const int c   = l & 31;
  const int h   = l >> 5;

  const size_t ebase = (size_t)b*ENK + ((size_t)(blk*4 + wv))*1024;
  const unsigned short* pbase = peh_ws + ebase*32 + (size_t)h*8*32 + c;

  f16v acc;
  #pragma unroll
  for (int i = 0; i < 16; ++i) acc[i] = 0.f;
  float spe = 0.f;
  const unsigned ONE = pkh(1.f, 1.f);

  #pragma unroll 2
  for (int t = 0; t < 64; ++t) {
    const unsigned short* p = pbase + (size_t)t*16*32;
    unsigned u0 = (unsigned)p[0*32]  | ((unsigned)p[1*32] << 16);
    unsigned u1 = (unsigned)p[2*32]  | ((unsigned)p[3*32] << 16);
    unsigned u2 = (unsigned)p[4*32]  | ((unsigned)p[5*32] << 16);
    unsigned u3 = (unsigned)p[6*32]  | ((unsigned)p[7*32] << 16);
    uint4 uu = make_uint4(u0, u1, u2, u3);
    h8v frag = __builtin_bit_cast(h8v, uu);
    acc = __builtin_amdgcn_mfma_f32_32x32x16_f16(frag, frag, acc, 0, 0, 0);
    spe = dot2f(u0, ONE, spe);
    spe = dot2f(u1, ONE, spe);
    spe = dot2f(u2, ONE, spe);
    spe = dot2f(u3, ONE, spe);
  }

  float* st2 = ws + WS_STATS2 + b*1056;
  spe += __shfl_down(spe, 32);
  if (l < 32) atomicAdd(st2 + c, spe);
  #pragma unroll
  for (int r = 0; r < 16; ++r) {
    int row = (r & 3) + 8*(r >> 2) + 4*h;
    atomicAdd(st2 + 32 + row*32 + c, acc[r]);
  }
}

// ---------------- Fold GN2 into Wa1, write half2-packed (natural order) ----------------
__global__ __launch_bounds__(64) void k_fold2m(
    const float* __restrict__ wa1, const float* __restrict__ ba1,
    const float* __restrict__ gw2, const float* __restrict__ gb2,
    float* __restrict__ ws)
{
  int b = blockIdx.x, o = threadIdx.x;
  const float* st = ws + WS_STATS2 + b*1056;
  float w[32];
  const float4* wrow = (const float4*)wa1 + o*8;
  #pragma unroll
  for (int i = 0; i < 8; ++i) {
    float4 t = wrow[i];
    w[4*i] = t.x; w[4*i+1] = t.y; w[4*i+2] = t.z; w[4*i+3] = t.w;
  }
  float dot = 0.f;
  #pragma unroll
  for (int cc = 0; cc < 32; ++cc) dot = fmaf(w[cc], st[cc], dot);
  float quad = 0.f;
  #pragma unroll
  for (int rr = 0; rr < 32; ++rr) {
    const float* Mr = st + 32 + rr*32;
    float mr = 0.f;
    #pragma unroll
    for (int cc = 0; cc < 32; ++cc) mr = fmaf(Mr[cc], w[cc], mr);
    quad = fmaf(w[rr], mr, quad);
  }
  float bb = ba1[o];
  float sum = dot + EF*bb;
  float ssq = quad + 2.f*bb*dot + EF*bb*bb;
  #pragma unroll
  for (int m = 1; m < 16; m <<= 1) {
    sum += __shfl_xor(sum, m);
    ssq += __shfl_xor(ssq, m);
  }
  float mu  = sum / CNTG;
  float var = ssq / CNTG - mu*mu;
  float sc  = rsqrtf(var + 1e-5f) * gw2[o];
  unsigned* dst = (unsigned*)ws + WS_WA1H + (b*64 + o)*16;
  #pragma unroll
  for (int i2 = 0; i2 < 16; ++i2) dst[i2] = pkh(w[2*i2]*sc, w[2*i2+1]*sc);
  (ws + WS_BA1F)[b*64 + o] = (bb - mu)*sc + gb2[o];
}

// ---------------- Pass C (MFMA): GEMM1 -> (no exchange) GEMM2 via delta-permuted Wa2 ----------------
__global__ __launch_bounds__(256) void k_out(
    const unsigned short* __restrict__ peh_ws, const int* __restrict__ mask,
    const float* __restrict__ ws, float* __restrict__ out)
{
  __shared__ float so[32][33];              // [j][32 n + pad]
  const int b  = blockIdx.x >> 10;          // 1024 blocks per batch (uniform)
  const int l  = threadIdx.x & 63;
  const int wv = threadIdx.x >> 6;
  const int c  = l & 31;
  const int h  = l >> 5;

  const unsigned* wa1h = (const unsigned*)ws + WS_WA1H + b*1024;
  const unsigned* wa2h = (const unsigned*)ws + WS_WA2H;
  uint4 A1[2][2], A2w[4];
  #pragma unroll
  for (int t = 0; t < 2; ++t)
    #pragma unroll
    for (int kc = 0; kc < 2; ++kc)
      A1[t][kc] = *(const uint4*)(wa1h + (c + 32*t)*16 + kc*8 + h*4);
  #pragma unroll
  for (int kc2 = 0; kc2 < 4; ++kc2)
    A2w[kc2] = *(const uint4*)(wa2h + (c*2 + h)*16 + kc2*4);

  const float* ba1f = ws + WS_BA1F + b*64;
  float bias1[2][16];
  #pragma unroll
  for (int t = 0; t < 2; ++t)
    #pragma unroll
    for (int r = 0; r < 16; ++r)
      bias1[t][r] = ba1f[(r&3) + 8*(r>>2) + 4*h + 32*t];

  const int e0w = blockIdx.x*512 + wv*128;

  #pragma unroll
  for (int tt = 0; tt < 4; ++tt) {
    const int e0 = e0w + tt*32;
    const unsigned short* peb = peh_ws + (size_t)(e0 + c)*32 + h*8;
    uint4 peB0 = *(const uint4*)peb;
    uint4 peB1 = *(const uint4*)(peb + 16);

    f16v acc1a, acc1b;
    #pragma unroll
    for (int r = 0; r < 16; ++r) { acc1a[r] = bias1[0][r]; acc1b[r] = bias1[1][r]; }
    acc1a = mfma16(A1[0][0], peB0, acc1a);
    acc1a = mfma16(A1[0][1], peB1, acc1a);
    acc1b = mfma16(A1[1][0], peB0, acc1b);
    acc1b = mfma16(A1[1][1], peB1, acc1b);

    // relu + pack -> GEMM2 A-frags directly (delta-permuted Wa2 pairs slot-wise; no exchange)
    unsigned u0[8], u1[8];
    #pragma unroll
    for (int p = 0; p < 8; ++p) {
      u0[p] = pkh(fmaxf(acc1a[2*p], 0.f), fmaxf(acc1a[2*p+1], 0.f));
      u1[p] = pkh(fmaxf(acc1b[2*p], 0.f), fmaxf(acc1b[2*p+1], 0.f));
    }

    f16v acc2;
    #pragma unroll
    for (int r = 0; r < 16; ++r) acc2[r] = 0.f;
    acc2 = mfma16(make_uint4(u0[0], u0[1], u0[2], u0[3]), A2w[0], acc2);
    acc2 = mfma16(make_uint4(u0[4], u0[5], u0[6], u0[7]), A2w[1], acc2);
    acc2 = mfma16(make_uint4(u1[0], u1[1], u1[2], u1[3]), A2w[2], acc2);
    acc2 = mfma16(make_uint4(u1[4], u1[5], u1[6], u1[7]), A2w[3], acc2);

    // mask -> finite -60 ; pe_r coalesced element-major loads
    float v[16], pe_r[16];
    #pragma unroll
    for (int g = 0; g < 4; ++g) {
      int eb = 8*g + 4*h;
      int4 mm = *(const int4*)(mask + e0 + eb);
      v[4*g+0] = mm.x ? acc2[4*g+0] : MASK_NEG;
      v[4*g+1] = mm.y ? acc2[4*g+1] : MASK_NEG;
      v[4*g+2] = mm.z ? acc2[4*g+2] : MASK_NEG;
      v[4*g+3] = mm.w ? acc2[4*g+3] : MASK_NEG;
      #pragma unroll
      for (int i = 0; i < 4; ++i)
        pe_r[4*g+i] = (float)*(const _Float16*)(peh_ws + (size_t)(e0 + eb + i)*32 + c);
    }

    float sA = 0.f, wA = 0.f, sB = 0.f, wB = 0.f;
    #pragma unroll
    for (int r = 0; r < 8; ++r) {
      float pa = __expf(v[r]);
      float pb = __expf(v[r+8]);
      sA += pa; wA = fmaf(pa, pe_r[r],   wA);
      sB += pb; wB = fmaf(pb, pe_r[r+8], wB);
    }
    sA += __shfl_xor(sA, 32); wA += __shfl_xor(wA, 32);
    sB += __shfl_xor(sB, 32); wB += __shfl_xor(wB, 32);

    float num = h ? wB : wA;
    float den = h ? sB : sA;
    so[c][wv*8 + tt*2 + h] = __fdividef(num, den);
  }

  __syncthreads();
  // coalesced writes: thread t writes 16B of one output row (32 rows x 32 n)
  const int n0 = (blockIdx.x & 1023) * 32;
  const int r = threadIdx.x >> 3, uu = threadIdx.x & 7;
  float4* dst = (float4*)(out + (size_t)b*(DIM*NN) + (size_t)r*NN + n0 + uu*4);
  dst[0] = *(float4*)&so[r][uu*4];
}

extern "C" void kernel_launch(void* const* d_in, const int* in_sizes, int n_in,
                              void* d_out, int out_size, void* d_ws, size_t ws_size,
                              hipStream_t stream) {
  (void)in_sizes; (void)n_in; (void)out_size; (void)ws_size;
  const float* q_xyzs   = (const float*)d_in[0];
  const float* k_xyzs   = (const float*)d_in[1];
  const int*   knn_idx  = (const int*)d_in[2];
  const int*   mask     = (const int*)d_in[3];
  const float* pre_w1   = (const float*)d_in[4];
  const float* pre_b1   = (const float*)d_in[5];
  const float* pre_gn_w = (const float*)d_in[6];
  const float* pre_gn_b = (const float*)d_in[7];
  const float* pre_w2   = (const float*)d_in[8];
  const float* pre_b2   = (const float*)d_in[9];
  const float* attn_w1  = (const float*)d_in[10];
  const float* attn_b1  = (const float*)d_in[11];
  const float* attn_gn_w= (const float*)d_in[12];
  const float* attn_gn_b= (const float*)d_in[13];
  const float* attn_w2  = (const float*)d_in[14];
  float* ws  = (float*)d_ws;
  float* out = (float*)d_out;
  unsigned short* peh_ws = (unsigned short*)((char*)d_ws + PE_BYTE_OFF);

  hipMemsetAsync(ws, 0, (64 + 4*1056)*sizeof(float), stream);
  k_lpmom <<<dim3(NB*256+1), 256, 0, stream>>>(q_xyzs, k_xyzs, knn_idx, pre_w2, attn_w2, ws);
  k_fold1 <<<dim3(NB),        64, 0, stream>>>(pre_w1, pre_b1, pre_gn_w, pre_gn_b, ws);
  k_pe    <<<dim3(NB*256),   256, 0, stream>>>(q_xyzs, k_xyzs, knn_idx, pre_b2, ws, peh_ws);
  k_pemom <<<dim3(NB*128),   256, 0, stream>>>(peh_ws, ws);
  k_fold2m<<<dim3(NB),        64, 0, stream>>>(attn_w1, attn_b1, attn_gn_w, attn_gn_b, ws);
  k_out   <<<dim3(NB*1024),  256, 0, stream>>>(peh_ws, mask, ws, out);
}

// Round 15
// 182.306 us; speedup vs baseline: 1.2342x; 1.0406x over previous
//
#include <hip/hip_runtime.h>
#include <hip/hip_bf16.h>
#include <math.h>

#define NB 4
#define NN 32768
#define MM 32768
#define KK 16
#define HID 64
#define DIM 32
#define ENK (NN*KK)              // 524288 elements per batch (2^19)
#define EF  524288.0f
#define CNTG (16.0f*EF)
#define MASK_NEG (-60.0f)        // finite mask: exp(-60)=8.8e-27; all-masked row -> exact uniform

// ---- workspace u32/float offsets (small region) ----
#define WS_STATS1 0        // [4][16]  : slp[4], M10[10], pad
#define WS_STATS2 64       // [4][1056]: spe[32], Mpe[32*32]
#define WS_B1F    5312     // [4][64] f32
#define WS_WA1H   5568     // [4][64][16] u32 (half2 folded attn_w1, natural order)
#define WS_BA1F   9664     // [4][64] f32
#define WS_W2H    9920     // [32][32] u32 (half2 pre_w2, natural slot order)
#define WS_WA2H   10944    // [32][2][16] u32 (half2 attn_w2, delta-permuted per (j,h))
#define WS_W1H    11968    // [4][64][2] u32 (half2 folded pre_w1)
#define PE_BYTE_OFF 65536ull
#define PE_BYTES (4ull*ENK*32ull*2ull)            // 134217728
#define LP_BYTE_OFF (PE_BYTE_OFF + PE_BYTES)      // lp cache: [4*ENK][2] u32 (f16x2 pairs)
#define LP_BYTES (4ull*ENK*8ull)                  // 16777216

typedef _Float16 h2v __attribute__((ext_vector_type(2)));
typedef _Float16 h8v __attribute__((ext_vector_type(8)));
typedef float f16v __attribute__((ext_vector_type(16)));

#if defined(__has_builtin)
#if __has_builtin(__builtin_amdgcn_fdot2)
#define USE_FDOT2 1
#endif
#endif
#ifndef USE_FDOT2
#define USE_FDOT2 0
#endif

__device__ __forceinline__ float dot2f(unsigned w, unsigned x, float acc) {
#if USE_FDOT2
  return __builtin_amdgcn_fdot2(__builtin_bit_cast(h2v, w),
                                __builtin_bit_cast(h2v, x), acc, false);
#else
  h2v a = __builtin_bit_cast(h2v, w);
  h2v b = __builtin_bit_cast(h2v, x);
  acc = fmaf((float)a[0], (float)b[0], acc);
  return fmaf((float)a[1], (float)b[1], acc);
#endif
}

__device__ __forceinline__ unsigned pkh(float a, float b) {
  return __builtin_bit_cast(unsigned, __builtin_amdgcn_cvt_pkrtz(a, b));
}

__device__ __forceinline__ f16v mfma16(uint4 a, uint4 b, f16v c) {
  return __builtin_amdgcn_mfma_f32_32x32x16_f16(
      __builtin_bit_cast(h8v, a), __builtin_bit_cast(h8v, b), c, 0, 0, 0);
}

template<int NV>
__device__ __forceinline__ void block_reduce_atomic(float* v, float* dst) {
  #pragma unroll
  for (int i = 0; i < NV; ++i) {
    float x = v[i];
    x += __shfl_down(x, 32);
    x += __shfl_down(x, 16);
    x += __shfl_down(x, 8);
    x += __shfl_down(x, 4);
    x += __shfl_down(x, 2);
    x += __shfl_down(x, 1);
    v[i] = x;
  }
  __shared__ float red[4][NV];
  const int lane = threadIdx.x & 63;
  const int wv = threadIdx.x >> 6;
  if (lane == 0) {
    #pragma unroll
    for (int i = 0; i < NV; ++i) red[wv][i] = v[i];
  }
  __syncthreads();
  if (threadIdx.x < NV) {
    float t = red[0][threadIdx.x] + red[1][threadIdx.x] +
              red[2][threadIdx.x] + red[3][threadIdx.x];
    atomicAdd(dst + threadIdx.x, t);
  }
}

__device__ __forceinline__ void compute_lp(const float* __restrict__ qb,
                                           const float* __restrict__ kb,
                                           int n, int idx,
                                           float& lp0, float& lp1, float& lp2, float& lp3) {
  float dx = kb[idx]        - qb[n];
  float dy = kb[MM + idx]   - qb[NN + n];
  float dz = kb[2*MM + idx] - qb[2*NN + n];
  float dist = sqrtf(fmaf(dx, dx, fmaf(dy, dy, dz*dz)));
  float inv = 1.0f / fmaxf(dist, 1e-12f);
  lp0 = dx * inv; lp1 = dy * inv; lp2 = dz * inv; lp3 = dist;
}

// ---------------- Pass A: lp moments (+ optional lp f16 cache); last block packs weights ----------------
__global__ __launch_bounds__(256) void k_lpmom(
    const float* __restrict__ q_xyzs, const float* __restrict__ k_xyzs,
    const int* __restrict__ knn_idx,
    const float* __restrict__ w2, const float* __restrict__ wa2,
    float* __restrict__ ws, unsigned* __restrict__ lp_ws, int store_lp)
{
  if (blockIdx.x == NB*256) {                 // weight-pack block
    int t = threadIdx.x;
    unsigned* wsu = (unsigned*)ws;
    if (t < 32) {
      const float* src = w2 + t*64;
      unsigned* dst = wsu + WS_W2H + t*32;
      #pragma unroll
      for (int i = 0; i < 32; ++i) dst[i] = pkh(src[2*i], src[2*i+1]);
    } else if (t >= 64 && t < 128) {
      // attn_w2 delta-permuted pack: slot (j, h, kc2, pb) = Wa2[j][delta], delta pairs (base,base+1)
      int j  = (t - 64) & 31;
      int hh = (t - 64) >> 5;
      const float* src = wa2 + j*64;
      unsigned* dst = wsu + WS_WA2H + (j*2 + hh)*16;
      #pragma unroll
      for (int kc2 = 0; kc2 < 4; ++kc2)
        #pragma unroll
        for (int pb = 0; pb < 4; ++pb) {
          int base = 32*(kc2>>1) + 16*(kc2&1) + 8*(pb>>1) + 4*hh + 2*(pb&1);
          dst[kc2*4 + pb] = pkh(src[base], src[base+1]);
        }
    }
    return;
  }
  const int b   = blockIdx.x >> 8;
  const int blk = blockIdx.x & 255;
  const float* qb = q_xyzs + b*3*NN;
  const float* kb = k_xyzs + b*3*MM;
  const int* idxb = knn_idx + b*ENK;

  float a[14];
  #pragma unroll
  for (int i = 0; i < 14; ++i) a[i] = 0.f;

  #pragma unroll
  for (int it = 0; it < 8; ++it) {
    int el = (blk*8 + it)*256 + threadIdx.x;
    int n = el >> 4;
    int idx = idxb[el];
    float lp0, lp1, lp2, lp3;
    compute_lp(qb, kb, n, idx, lp0, lp1, lp2, lp3);
    if (store_lp) {
      uint2 v = make_uint2(pkh(lp0, lp1), pkh(lp2, lp3));
      *(uint2*)(lp_ws + (size_t)(b*ENK + el)*2) = v;
    }
    a[0] += lp0; a[1] += lp1; a[2] += lp2; a[3] += lp3;
    a[4] = fmaf(lp0, lp0, a[4]);  a[5] = fmaf(lp0, lp1, a[5]);
    a[6] = fmaf(lp0, lp2, a[6]);  a[7] = fmaf(lp0, lp3, a[7]);
    a[8] = fmaf(lp1, lp1, a[8]);  a[9] = fmaf(lp1, lp2, a[9]);
    a[10] = fmaf(lp1, lp3, a[10]); a[11] = fmaf(lp2, lp2, a[11]);
    a[12] = fmaf(lp2, lp3, a[12]); a[13] = fmaf(lp3, lp3, a[13]);
  }
  block_reduce_atomic<14>(a, ws + WS_STATS1 + b*16);
}

// ---------------- Fold GN1 into W1 (writes half2-packed + f32 bias) ----------------
__global__ __launch_bounds__(64) void k_fold1(
    const float* __restrict__ w1, const float* __restrict__ b1,
    const float* __restrict__ gw, const float* __restrict__ gb,
    float* __restrict__ ws)
{
  int b = blockIdx.x, o = threadIdx.x;
  const float* st = ws + WS_STATS1 + b*16;
  float4 w = ((const float4*)w1)[o];
  float bb = b1[o];
  float dot = w.x*st[0] + w.y*st[1] + w.z*st[2] + w.w*st[3];
  float quad = w.x*w.x*st[4] + w.y*w.y*st[8] + w.z*w.z*st[11] + w.w*w.w*st[13]
    + 2.f*(w.x*w.y*st[5] + w.x*w.z*st[6] + w.x*w.w*st[7]
         + w.y*w.z*st[9] + w.y*w.w*st[10] + w.z*w.w*st[12]);
  float sum = dot + EF*bb;
  float ssq = quad + 2.f*bb*dot + EF*bb*bb;
  #pragma unroll
  for (int m = 1; m < 16; m <<= 1) {
    sum += __shfl_xor(sum, m);
    ssq += __shfl_xor(ssq, m);
  }
  float mu  = sum / CNTG;
  float var = ssq / CNTG - mu*mu;
  float sc  = rsqrtf(var + 1e-5f) * gw[o];
  unsigned* w1hd = (unsigned*)ws + WS_W1H + b*128;
  w1hd[o*2]   = pkh(w.x*sc, w.y*sc);
  w1hd[o*2+1] = pkh(w.z*sc, w.w*sc);
  (ws + WS_B1F)[b*64 + o] = (bb - mu)*sc + gb[o];
}

// ---------------- Pass B (MFMA): lp -> h1 -> pe = W2 h1 + b2, store f16 element-major ----------------
// grid NB*256, 16 tiles of 32 per wave; lp cached (coalesced 8B load) or gathered (fallback).
__global__ __launch_bounds__(256) void k_pe(
    const float* __restrict__ q_xyzs, const float* __restrict__ k_xyzs,
    const int* __restrict__ knn_idx, const float* __restrict__ b2,
    const float* __restrict__ ws, unsigned short* __restrict__ peh_ws,
    const unsigned* __restrict__ lp_ws, int uselp)
{
  const int b  = blockIdx.x >> 8;           // 256 blocks per batch (uniform)
  const int l  = threadIdx.x & 63;
  const int wv = threadIdx.x >> 6;
  const int c  = l & 31;
  const int h  = l >> 5;
  const float* qb = q_xyzs + b*3*NN;
  const float* kb = k_xyzs + b*3*MM;

  const unsigned* w1h = (const unsigned*)ws + WS_W1H + b*128;
  const float* b1f = ws + WS_B1F + b*64;
  unsigned w01[32], w23[32];
  float bch[32];
  #pragma unroll
  for (int kc = 0; kc < 4; ++kc)
    #pragma unroll
    for (int jj = 0; jj < 8; ++jj) {
      int ch = kc*16 + h*8 + jj;
      w01[kc*8+jj] = w1h[ch*2];
      w23[kc*8+jj] = w1h[ch*2+1];
      bch[kc*8+jj] = b1f[ch];
    }
  const unsigned* w2h = (const unsigned*)ws + WS_W2H;
  uint4 A2[4];
  #pragma unroll
  for (int kc = 0; kc < 4; ++kc)
    A2[kc] = *(const uint4*)(w2h + c*32 + kc*8 + h*4);
  float bias2[16];
  #pragma unroll
  for (int r = 0; r < 16; ++r) bias2[r] = b2[(r&3) + 8*(r>>2) + 4*h];

  const int e0w = blockIdx.x*2048 + wv*512;

  #pragma unroll 2
  for (int tt = 0; tt < 16; ++tt) {
    const int e = e0w + tt*32 + c;
    unsigned lp01, lp23;
    if (uselp) {
      uint2 v = *(const uint2*)(lp_ws + (size_t)e*2);
      lp01 = v.x; lp23 = v.y;
    } else {
      int n = (e & (ENK-1)) >> 4;
      int idx = knn_idx[e];
      float lp0, lp1, lp2, lp3;
      compute_lp(qb, kb, n, idx, lp0, lp1, lp2, lp3);
      lp01 = pkh(lp0, lp1); lp23 = pkh(lp2, lp3);
    }

    uint4 Bf[4];
    #pragma unroll
    for (int kc = 0; kc < 4; ++kc) {
      unsigned bb[4];
      #pragma unroll
      for (int q = 0; q < 4; ++q) {
        int i0 = kc*8 + 2*q, i1 = i0 + 1;
        float xa = fmaxf(dot2f(w01[i0], lp01, dot2f(w23[i0], lp23, bch[i0])), 0.f);
        float xb = fmaxf(dot2f(w01[i1], lp01, dot2f(w23[i1], lp23, bch[i1])), 0.f);
        bb[q] = pkh(xa, xb);
      }
      Bf[kc] = make_uint4(bb[0], bb[1], bb[2], bb[3]);
    }

    f16v acc;
    #pragma unroll
    for (int r = 0; r < 16; ++r) acc[r] = bias2[r];
    #pragma unroll
    for (int kc = 0; kc < 4; ++kc) acc = mfma16(A2[kc], Bf[kc], acc);

    // pack row pairs, shfl cross-half, assemble element-major, store
    unsigned u[8], x[8];
    #pragma unroll
    for (int p = 0; p < 8; ++p) u[p] = pkh(acc[2*p], acc[2*p+1]);
    #pragma unroll
    for (int p = 0; p < 8; ++p) x[p] = __shfl_xor(u[p], 32);
    uint4 f0, f1;
    f0.x = h ? x[4] : u[0];  f0.y = h ? x[5] : u[1];
    f0.z = h ? u[4] : x[0];  f0.w = h ? u[5] : x[1];
    f1.x = h ? x[6] : u[2];  f1.y = h ? x[7] : u[3];
    f1.z = h ? u[6] : x[2];  f1.w = h ? u[7] : x[3];
    uint4* d = (uint4*)(peh_ws + (size_t)e*32 + h*16);
    d[0] = f0;
    d[1] = f1;
  }
}

// ---------------- Pass B2: pe moments via MFMA (M = pe^T pe, spe = sum pe) ----------------
__global__ __launch_bounds__(256) void k_pemom(
    const unsigned short* __restrict__ peh_ws, float* __restrict__ ws)
{
  const int b   = blockIdx.x >> 7;          // 128 blocks per batch
  const int blk = blockIdx.x & 127;
  const int wv  = threadIdx.x >> 6;
  const int l   = threadIdx.x & 63;
  const int c   = l & 31;
  const int h   = l >> 5;

  const size_t ebase = (size_t)b*ENK + ((size_t)(blk*4 + wv))*1024;
  const unsigned short* pbase = peh_ws + ebase*32 + (size_t)h*8*32 + c;

  f16v acc;
  #pragma unroll
  for (int i = 0; i < 16; ++i) acc[i] = 0.f;
  float spe = 0.f;
  const unsigned ONE = pkh(1.f, 1.f);

  #pragma unroll 2
  for (int t = 0; t < 64; ++t) {
    const unsigned short* p = pbase + (size_t)t*16*32;
    unsigned u0 = (unsigned)p[0*32]  | ((unsigned)p[1*32] << 16);
    unsigned u1 = (unsigned)p[2*32]  | ((unsigned)p[3*32] << 16);
    unsigned u2 = (unsigned)p[4*32]  | ((unsigned)p[5*32] << 16);
    unsigned u3 = (unsigned)p[6*32]  | ((unsigned)p[7*32] << 16);
    uint4 uu = make_uint4(u0, u1, u2, u3);
    h8v frag = __builtin_bit_cast(h8v, uu);
    acc = __builtin_amdgcn_mfma_f32_32x32x16_f16(frag, frag, acc, 0, 0, 0);
    spe = dot2f(u0, ONE, spe);
    spe = dot2f(u1, ONE, spe);
    spe = dot2f(u2, ONE, spe);
    spe = dot2f(u3, ONE, spe);
  }

  float* st2 = ws + WS_STATS2 + b*1056;
  spe += __shfl_down(spe, 32);
  if (l < 32) atomicAdd(st2 + c, spe);
  #pragma unroll
  for (int r = 0; r < 16; ++r) {
    int row = (r & 3) + 8*(r >> 2) + 4*h;
    atomicAdd(st2 + 32 + row*32 + c, acc[r]);
  }
}

// ---------------- Fold GN2 into Wa1, write half2-packed (natural order) ----------------
__global__ __launch_bounds__(64) void k_fold2m(
    const float* __restrict__ wa1, const float* __restrict__ ba1,
    const float* __restrict__ gw2, const float* __restrict__ gb2,
    float* __restrict__ ws)
{
  int b = blockIdx.x, o = threadIdx.x;
  const float* st = ws + WS_STATS2 + b*1056;
  float w[32];
  const float4* wrow = (const float4*)wa1 + o*8;
  #pragma unroll
  for (int i = 0; i < 8; ++i) {
    float4 t = wrow[i];
    w[4*i] = t.x; w[4*i+1] = t.y; w[4*i+2] = t.z; w[4*i+3] = t.w;
  }
  float dot = 0.f;
  #pragma unroll
  for (int cc = 0; cc < 32; ++cc) dot = fmaf(w[cc], st[cc], dot);
  float quad = 0.f;
  #pragma unroll
  for (int rr = 0; rr < 32; ++rr) {
    const float* Mr = st + 32 + rr*32;
    float mr = 0.f;
    #pragma unroll
    for (int cc = 0; cc < 32; ++cc) mr = fmaf(Mr[cc], w[cc], mr);
    quad = fmaf(w[rr], mr, quad);
  }
  float bb = ba1[o];
  float sum = dot + EF*bb;
  float ssq = quad + 2.f*bb*dot + EF*bb*bb;
  #pragma unroll
  for (int m = 1; m < 16; m <<= 1) {
    sum += __shfl_xor(sum, m);
    ssq += __shfl_xor(ssq, m);
  }
  float mu  = sum / CNTG;
  float var = ssq / CNTG - mu*mu;
  float sc  = rsqrtf(var + 1e-5f) * gw2[o];
  unsigned* dst = (unsigned*)ws + WS_WA1H + (b*64 + o)*16;
  #pragma unroll
  for (int i2 = 0; i2 < 16; ++i2) dst[i2] = pkh(w[2*i2]*sc, w[2*i2+1]*sc);
  (ws + WS_BA1F)[b*64 + o] = (bb - mu)*sc + gb2[o];
}

// ---------------- Pass C (MFMA): GEMM1 -> (no exchange) GEMM2 via delta-permuted Wa2 ----------------
__global__ __launch_bounds__(256) void k_out(
    const unsigned short* __restrict__ peh_ws, const int* __restrict__ mask,
    const float* __restrict__ ws, float* __restrict__ out)
{
  __shared__ float so[32][33];              // [j][32 n + pad]
  const int b  = blockIdx.x >> 10;          // 1024 blocks per batch (uniform)
  const int l  = threadIdx.x & 63;
  const int wv = threadIdx.x >> 6;
  const int c  = l & 31;
  const int h  = l >> 5;

  const unsigned* wa1h = (const unsigned*)ws + WS_WA1H + b*1024;
  const unsigned* wa2h = (const unsigned*)ws + WS_WA2H;
  uint4 A1[2][2], A2w[4];
  #pragma unroll
  for (int t = 0; t < 2; ++t)
    #pragma unroll
    for (int kc = 0; kc < 2; ++kc)
      A1[t][kc] = *(const uint4*)(wa1h + (c + 32*t)*16 + kc*8 + h*4);
  #pragma unroll
  for (int kc2 = 0; kc2 < 4; ++kc2)
    A2w[kc2] = *(const uint4*)(wa2h + (c*2 + h)*16 + kc2*4);

  const float* ba1f = ws + WS_BA1F + b*64;
  float bias1[2][16];
  #pragma unroll
  for (int t = 0; t < 2; ++t)
    #pragma unroll
    for (int r = 0; r < 16; ++r)
      bias1[t][r] = ba1f[(r&3) + 8*(r>>2) + 4*h + 32*t];

  const int e0w = blockIdx.x*512 + wv*128;

  #pragma unroll
  for (int tt = 0; tt < 4; ++tt) {
    const int e0 = e0w + tt*32;
    const unsigned short* peb = peh_ws + (size_t)(e0 + c)*32 + h*8;
    uint4 peB0 = *(const uint4*)peb;
    uint4 peB1 = *(const uint4*)(peb + 16);

    f16v acc1a, acc1b;
    #pragma unroll
    for (int r = 0; r < 16; ++r) { acc1a[r] = bias1[0][r]; acc1b[r] = bias1[1][r]; }
    acc1a = mfma16(A1[0][0], peB0, acc1a);
    acc1a = mfma16(A1[0][1], peB1, acc1a);
    acc1b = mfma16(A1[1][0], peB0, acc1b);
    acc1b = mfma16(A1[1][1], peB1, acc1b);

    // relu + pack -> GEMM2 A-frags directly (delta-permuted Wa2 pairs slot-wise; no exchange)
    unsigned u0[8], u1[8];
    #pragma unroll
    for (int p = 0; p < 8; ++p) {
      u0[p] = pkh(fmaxf(acc1a[2*p], 0.f), fmaxf(acc1a[2*p+1], 0.f));
      u1[p] = pkh(fmaxf(acc1b[2*p], 0.f), fmaxf(acc1b[2*p+1], 0.f));
    }

    f16v acc2;
    #pragma unroll
    for (int r = 0; r < 16; ++r) acc2[r] = 0.f;
    acc2 = mfma16(make_uint4(u0[0], u0[1], u0[2], u0[3]), A2w[0], acc2);
    acc2 = mfma16(make_uint4(u0[4], u0[5], u0[6], u0[7]), A2w[1], acc2);
    acc2 = mfma16(make_uint4(u1[0], u1[1], u1[2], u1[3]), A2w[2], acc2);
    acc2 = mfma16(make_uint4(u1[4], u1[5], u1[6], u1[7]), A2w[3], acc2);

    // mask -> finite -60 ; pe_r coalesced element-major loads
    float v[16], pe_r[16];
    #pragma unroll
    for (int g = 0; g < 4; ++g) {
      int eb = 8*g + 4*h;
      int4 mm = *(const int4*)(mask + e0 + eb);
      v[4*g+0] = mm.x ? acc2[4*g+0] : MASK_NEG;
      v[4*g+1] = mm.y ? acc2[4*g+1] : MASK_NEG;
      v[4*g+2] = mm.z ? acc2[4*g+2] : MASK_NEG;
      v[4*g+3] = mm.w ? acc2[4*g+3] : MASK_NEG;
      #pragma unroll
      for (int i = 0; i < 4; ++i)
        pe_r[4*g+i] = (float)*(const _Float16*)(peh_ws + (size_t)(e0 + eb + i)*32 + c);
    }

    float sA = 0.f, wA = 0.f, sB = 0.f, wB = 0.f;
    #pragma unroll
    for (int r = 0; r < 8; ++r) {
      float pa = __expf(v[r]);
      float pb = __expf(v[r+8]);
      sA += pa; wA = fmaf(pa, pe_r[r],   wA);
      sB += pb; wB = fmaf(pb, pe_r[r+8], wB);
    }
    sA += __shfl_xor(sA, 32); wA += __shfl_xor(wA, 32);
    sB += __shfl_xor(sB, 32); wB += __shfl_xor(wB, 32);

    float num = h ? wB : wA;
    float den = h ? sB : sA;
    so[c][wv*8 + tt*2 + h] = __fdividef(num, den);
  }

  __syncthreads();
  // coalesced writes: thread t writes 16B of one output row (32 rows x 32 n)
  const int n0 = (blockIdx.x & 1023) * 32;
  const int r = threadIdx.x >> 3, uu = threadIdx.x & 7;
  float4* dst = (float4*)(out + (size_t)b*(DIM*NN) + (size_t)r*NN + n0 + uu*4);
  dst[0] = *(float4*)&so[r][uu*4];
}

extern "C" void kernel_launch(void* const* d_in, const int* in_sizes, int n_in,
                              void* d_out, int out_size, void* d_ws, size_t ws_size,
                              hipStream_t stream) {
  (void)in_sizes; (void)n_in; (void)out_size;
  const float* q_xyzs   = (const float*)d_in[0];
  const float* k_xyzs   = (const float*)d_in[1];
  const int*   knn_idx  = (const int*)d_in[2];
  const int*   mask     = (const int*)d_in[3];
  const float* pre_w1   = (const float*)d_in[4];
  const float* pre_b1   = (const float*)d_in[5];
  const float* pre_gn_w = (const float*)d_in[6];
  const float* pre_gn_b = (const float*)d_in[7];
  const float* pre_w2   = (const float*)d_in[8];
  const float* pre_b2   = (const float*)d_in[9];
  const float* attn_w1  = (const float*)d_in[10];
  const float* attn_b1  = (const float*)d_in[11];
  const float* attn_gn_w= (const float*)d_in[12];
  const float* attn_gn_b= (const float*)d_in[13];
  const float* attn_w2  = (const float*)d_in[14];
  float* ws  = (float*)d_ws;
  float* out = (float*)d_out;
  unsigned short* peh_ws = (unsigned short*)((char*)d_ws + PE_BYTE_OFF);
  unsigned* lp_ws = (unsigned*)((char*)d_ws + LP_BYTE_OFF);
  const int has_lp = (ws_size >= (size_t)(LP_BYTE_OFF + LP_BYTES)) ? 1 : 0;

  hipMemsetAsync(ws, 0, (64 + 4*1056)*sizeof(float), stream);
  k_lpmom <<<dim3(NB*256+1), 256, 0, stream>>>(q_xyzs, k_xyzs, knn_idx, pre_w2, attn_w2, ws, lp_ws, has_lp);
  k_fold1 <<<dim3(NB),        64, 0, stream>>>(pre_w1, pre_b1, pre_gn_w, pre_gn_b, ws);
  k_pe    <<<dim3(NB*256),   256, 0, stream>>>(q_xyzs, k_xyzs, knn_idx, pre_b2, ws, peh_ws, lp_ws, has_lp);
  k_pemom <<<dim3(NB*128),   256, 0, stream>>>(peh_ws, ws);
  k_fold2m<<<dim3(NB),        64, 0, stream>>>(attn_w1, attn_b1, attn_gn_w, attn_gn_b, ws);
  k_out   <<<dim3(NB*1024),  256, 0, stream>>>(peh_ws, mask, ws, out);
}